// Round 6
// baseline (284.256 us; speedup 1.0000x reference)
//
#include <hip/hip_runtime.h>
#include <hip/hip_bf16.h>

#define BB 8
#define NN 512
#define DINC 128
#define DOUTC 128
#define HHC 8
#define EEC 16
#define DHC 16

typedef _Float16 h4 __attribute__((ext_vector_type(4)));
typedef float f32x4 __attribute__((ext_vector_type(4)));

__device__ __forceinline__ float wsum(float v){
#pragma unroll
  for (int o=1;o<64;o<<=1) v += __shfl_xor(v,o);
  return v;
}

// ---------- LN1 + Wp + Q/K/V projections: 8 rows per 128-thread block ----------
// Q,K written [b,h,n,d]; V written TRANSPOSED [b,h,d,n] for the fused kernel.
__global__ __launch_bounds__(128) void k_proj(
    const float* __restrict__ x,
    const float* __restrict__ g1, const float* __restrict__ b1,
    const float* __restrict__ Wp, const float* __restrict__ bp,
    const float* __restrict__ Wq, const float* __restrict__ Wk, const float* __restrict__ Wv,
    float* __restrict__ xp, _Float16* __restrict__ Qh, _Float16* __restrict__ Kh, _Float16* __restrict__ Vt)
{
  const int R = 8, P = 12;
  __shared__ float xln[DINC*P];
  __shared__ float xps[DINC*P];
  __shared__ float part[2][R][2];
  int tid = threadIdx.x, w = tid>>6, lane = tid&63;
  int row0 = blockIdx.x * R;
  float v[R];
#pragma unroll
  for (int r=0;r<R;++r) v[r] = x[(size_t)(row0+r)*DINC + tid];
  float gg = g1[tid], bbv = b1[tid];
#pragma unroll
  for (int r=0;r<R;++r){
    float s = wsum(v[r]);
    float q = wsum(v[r]*v[r]);
    if (lane==0){ part[w][r][0]=s; part[w][r][1]=q; }
  }
  __syncthreads();
#pragma unroll
  for (int r=0;r<R;++r){
    float s = part[0][r][0]+part[1][r][0];
    float q = part[0][r][1]+part[1][r][1];
    float mean = s*(1.f/DINC);
    float var  = q*(1.f/DINC) - mean*mean;
    float rstd = rsqrtf(var + 1e-5f);
    xln[tid*P + r] = (v[r]-mean)*rstd*gg + bbv;
  }
  __syncthreads();
  int j = tid;
  float acc[R];
  {
    float bj = bp[j];
#pragma unroll
    for (int r=0;r<R;++r) acc[r]=bj;
    for (int i=0;i<DINC;++i){
      float wv = Wp[i*DOUTC + j];
      const float4* xa = (const float4*)&xln[i*P];
      float4 a = xa[0], b = xa[1];
      acc[0]+=a.x*wv; acc[1]+=a.y*wv; acc[2]+=a.z*wv; acc[3]+=a.w*wv;
      acc[4]+=b.x*wv; acc[5]+=b.y*wv; acc[6]+=b.z*wv; acc[7]+=b.w*wv;
    }
#pragma unroll
    for (int r=0;r<R;++r){
      xps[j*P + r] = acc[r];
      xp[(size_t)(row0+r)*DOUTC + j] = acc[r];
    }
  }
  __syncthreads();
  const float* Ws[3] = {Wq, Wk, Wv};
#pragma unroll
  for (int mmat=0;mmat<3;++mmat){
    const float* W = Ws[mmat];
#pragma unroll
    for (int r=0;r<R;++r) acc[r]=0.f;
    for (int i=0;i<DINC;++i){
      float wv = W[i*DOUTC + j];
      const float4* xa = (const float4*)&xps[i*P];
      float4 a = xa[0], b = xa[1];
      acc[0]+=a.x*wv; acc[1]+=a.y*wv; acc[2]+=a.z*wv; acc[3]+=a.w*wv;
      acc[4]+=b.x*wv; acc[5]+=b.y*wv; acc[6]+=b.z*wv; acc[7]+=b.w*wv;
    }
    int h = j>>4, d = j&15;
#pragma unroll
    for (int r=0;r<R;++r){
      int row = row0+r; int bidx = row>>9, n = row&(NN-1);
      if (mmat==0)      Qh[(((size_t)bidx*HHC + h)*NN + n)*DHC + d] = (_Float16)acc[r];
      else if (mmat==1) Kh[(((size_t)bidx*HHC + h)*NN + n)*DHC + d] = (_Float16)acc[r];
      else              Vt[(((size_t)bidx*HHC + h)*DHC + d)*NN + n] = (_Float16)acc[r];
    }
  }
}

// ---------- FUSED edge-MLP + attention, v3 ----------
// Same as R5 v2 but ea double-buffer uses STATIC named register arrays in a
// fully-unrolled 2-step loop (R5's runtime-indexed er[2][4] spilled to scratch:
// 138MB of VMEM scratch traffic, rule #20).
__global__ __launch_bounds__(256,4) void k_fused(
  const float* __restrict__ ea, const int* __restrict__ adj,
  const float* __restrict__ eg, const float* __restrict__ ebi,
  const float* __restrict__ We1, const float* __restrict__ be1,
  const float* __restrict__ We2, const float* __restrict__ be2,
  const _Float16* __restrict__ Qh, const _Float16* __restrict__ Kh,
  const _Float16* __restrict__ Vt, float* __restrict__ ctxb)
{
  __shared__ _Float16 biasL[2][8][4][72];      // [buf][h][n][m pad72] 9.2KB
  __shared__ unsigned long long mrow[4][8];

  int tid = threadIdx.x, w = tid>>6, lane = tid&63;
  int c = lane&15, g = lane>>4;
  int blk = blockIdx.x;
  int b = blk>>7, tile = blk&127;
  int n0 = tile*4;

  // adjacency bitmask (+self loop) for the 4 rows
#pragma unroll
  for (int k=0;k<4;++k){
    int row = n0+k;
#pragma unroll
    for (int half=0;half<2;++half){
      int col = half*256 + tid;
      int val = (adj[((size_t)b*NN + row)*NN + col] != 0) || (col == row);
      unsigned long long bal = __ballot(val);
      if (lane==0) mrow[k][half*4 + w] = bal;
    }
  }

  // MLP weight A-fragments (transposed-layer trick, verified R3/R4)
  h4 w1a,w1b,w2a,w2b;
#pragma unroll
  for (int j=0;j<4;++j){
    w1a[j] = (_Float16)We1[(4*g+j)*32 + c];
    w1b[j] = (_Float16)We1[(4*g+j)*32 + 16 + c];
    w2a[j] = (_Float16)((c<8)? We2[(4*g+j)*HHC + c] : 0.f);
    w2b[j] = (_Float16)((c<8)? We2[(16+4*g+j)*HHC + c] : 0.f);
  }
  float4 b1a = *(const float4*)(be1 + 4*g);
  float4 b1b = *(const float4*)(be1 + 16 + 4*g);
  float4 b2r = *(const float4*)(be2 + (g&1)*4);
  float4 G4  = *(const float4*)(eg  + 4*g);
  float4 Bv4 = *(const float4*)(ebi + 4*g);

  // Q B-fragments for this wave's two heads (4 valid rows, c&3; cols 4-15 dup)
  int h0 = w, h1 = w+4;
  h4 qf0 = *(const h4*)(Qh + (((size_t)b*HHC + h0)*NN + n0 + (c&3))*DHC + 4*g);
  h4 qf1 = *(const h4*)(Qh + (((size_t)b*HHC + h1)*NN + n0 + (c&3))*DHC + 4*g);

  const float* eaRow = ea + (((size_t)b*NN + n0 + w)*NN)*EEC;   // wave's MLP row

  f32x4 acc0 = {0.f,0.f,0.f,0.f}, acc1 = {0.f,0.f,0.f,0.f};
  float rs0 = 0.f, rs1 = 0.f;

  float4 erA0,erA1,erA2,erA3, erB0,erB1,erB2,erB3;   // static double-buffer
  erA0 = *(const float4*)(eaRow + (size_t)( 0*16 + c)*EEC + 4*g);
  erA1 = *(const float4*)(eaRow + (size_t)( 1*16 + c)*EEC + 4*g);
  erA2 = *(const float4*)(eaRow + (size_t)( 2*16 + c)*EEC + 4*g);
  erA3 = *(const float4*)(eaRow + (size_t)( 3*16 + c)*EEC + 4*g);

  __syncthreads();   // mrow visible

  // ---- MLP for chunk ch from 4 static float4s -> biasL[ch&1]
  auto MLP = [&](int ch, float4 e0, float4 e1, float4 e2, float4 e3){
    int buf = ch & 1;
    unsigned long long wm = mrow[w][ch];
    float4 ee[4] = {e0,e1,e2,e3};        // static-indexed below (unrolled)
#pragma unroll
    for (int mg=0;mg<4;++mg){
      float4 v = ee[mg];
      float s = v.x+v.y+v.z+v.w;
      float q = v.x*v.x+v.y*v.y+v.z*v.z+v.w*v.w;
      s += __shfl_xor(s,16); s += __shfl_xor(s,32);
      q += __shfl_xor(q,16); q += __shfl_xor(q,32);
      float mean = s*(1.f/EEC);
      float var  = q*(1.f/EEC) - mean*mean;
      float rstd = rsqrtf(var + 1e-5f);
      h4 ef;
      ef[0]=(_Float16)((v.x-mean)*rstd*G4.x + Bv4.x);
      ef[1]=(_Float16)((v.y-mean)*rstd*G4.y + Bv4.y);
      ef[2]=(_Float16)((v.z-mean)*rstd*G4.z + Bv4.z);
      ef[3]=(_Float16)((v.w-mean)*rstd*G4.w + Bv4.w);
      f32x4 d1a = {b1a.x,b1a.y,b1a.z,b1a.w};
      f32x4 d1b = {b1b.x,b1b.y,b1b.z,b1b.w};
      d1a = __builtin_amdgcn_mfma_f32_16x16x16f16(w1a, ef, d1a, 0,0,0);
      d1b = __builtin_amdgcn_mfma_f32_16x16x16f16(w1b, ef, d1b, 0,0,0);
      h4 hfa,hfb;
#pragma unroll
      for (int r=0;r<4;++r){
        hfa[r]=(_Float16)fmaxf(d1a[r],0.f);
        hfb[r]=(_Float16)fmaxf(d1b[r],0.f);
      }
      f32x4 d2 = {0.f,0.f,0.f,0.f};
      d2 = __builtin_amdgcn_mfma_f32_16x16x16f16(w2a, hfa, d2, 0,0,0);
      d2 = __builtin_amdgcn_mfma_f32_16x16x16f16(w2b, hfb, d2, 0,0,0);
      if (g<2){
#pragma unroll
        for (int r=0;r<4;++r){
          float y = d2[r] + ((const float*)&b2r)[r];
          y = fminf(fmaxf(2.f*y,-30.f),30.f);
          float ex = __expf(y);
          float t = (ex-1.f)/(ex+1.f);                 // tanh
          bool ok = (wm >> (mg*16+c)) & 1ull;
          biasL[buf][4*g+r][w][mg*16+c] = ok ? (_Float16)(5.f*t) : (_Float16)(-30000.f);
        }
      }
    }
  };

  // ---- attention on chunk ch, heads h0,h1 (accumulates acc0/1, rs0/1)
  auto ATTN = [&](int ch){
#pragma unroll
    for (int hh=0; hh<2; ++hh){
      int head = hh ? h1 : h0;
      h4 qf = hh ? qf1 : qf0;
      const _Float16* Kb = Kh + (((size_t)b*HHC + head)*NN + ch*64)*DHC;
      const _Float16* Vb = Vt + (((size_t)b*HHC + head)*DHC + c)*NN + ch*64;
      const _Float16* bb = &biasL[ch&1][head][c&3][0];
      f32x4 a = hh ? acc1 : acc0;
      float rs = 0.f;
#pragma unroll
      for (int t=0;t<4;++t){
        h4 kf = *(const h4*)(Kb + (16*t + c)*DHC + 4*g);
        f32x4 zero = {0.f,0.f,0.f,0.f};
        f32x4 d = __builtin_amdgcn_mfma_f32_16x16x16f16(kf, qf, zero, 0,0,0);
        h4 e4 = *(const h4*)(bb + 16*t + 4*g);
        h4 pa;
#pragma unroll
        for (int r=0;r<4;++r){
          float sv = d[r]*0.25f + (float)e4[r];
          sv = fmaxf(sv,0.f) + 0.2f*fminf(sv,0.f);     // LeakyReLU(0.2)
          float p = __expf(sv - 6.f);
          rs += p;
          pa[r] = (_Float16)p;
        }
        h4 vf = *(const h4*)(Vb + 16*t + 4*g);
        a = __builtin_amdgcn_mfma_f32_16x16x16f16(pa, vf, a, 0,0,0);
      }
      if (hh){ acc1 = a; rs1 += rs; } else { acc0 = a; rs0 += rs; }
    }
  };

  MLP(0, erA0, erA1, erA2, erA3);        // produce chunk 0

#pragma unroll
  for (int cc=0; cc<4; ++cc){
    { // even chunk ch=2cc: consume A, prefetch+produce B
      const int ch = 2*cc;
      erB0 = *(const float4*)(eaRow + (size_t)((ch+1)*64 +  0 + c)*EEC + 4*g);
      erB1 = *(const float4*)(eaRow + (size_t)((ch+1)*64 + 16 + c)*EEC + 4*g);
      erB2 = *(const float4*)(eaRow + (size_t)((ch+1)*64 + 32 + c)*EEC + 4*g);
      erB3 = *(const float4*)(eaRow + (size_t)((ch+1)*64 + 48 + c)*EEC + 4*g);
      __syncthreads();                   // biasL[ch&1] ready
      ATTN(ch);
      MLP(ch+1, erB0, erB1, erB2, erB3);
    }
    { // odd chunk ch=2cc+1: consume B, prefetch+produce A
      const int ch = 2*cc+1;
      if (ch<7){
        erA0 = *(const float4*)(eaRow + (size_t)((ch+1)*64 +  0 + c)*EEC + 4*g);
        erA1 = *(const float4*)(eaRow + (size_t)((ch+1)*64 + 16 + c)*EEC + 4*g);
        erA2 = *(const float4*)(eaRow + (size_t)((ch+1)*64 + 32 + c)*EEC + 4*g);
        erA3 = *(const float4*)(eaRow + (size_t)((ch+1)*64 + 48 + c)*EEC + 4*g);
      }
      __syncthreads();                   // biasL[ch&1] ready
      ATTN(ch);
      if (ch<7) MLP(ch+1, erA0, erA1, erA2, erA3);
    }
  }

  // rowsum: reduce over g-copies ONLY (c-copies hold identical sums)
  rs0 += __shfl_xor(rs0,16); rs0 += __shfl_xor(rs0,32);
  rs1 += __shfl_xor(rs1,16); rs1 += __shfl_xor(rs1,32);
  float s0r[4], s1r[4];
#pragma unroll
  for (int r=0;r<4;++r){ s0r[r]=__shfl(rs0,r); s1r[r]=__shfl(rs1,r); }

  // ctx D-layout: lane(c,g) holds rows n=4g+r (valid g==0), d=c
  if (g==0){
#pragma unroll
    for (int r=0;r<4;++r){
      size_t rowoff = ((size_t)b*NN + n0 + r)*DOUTC;
      ctxb[rowoff + h0*DHC + c] = acc0[r]/s0r[r];
      ctxb[rowoff + h1*DHC + c] = acc1[r]/s1r[r];
    }
  }
}

// ---------- h = xp+ctx; LN2; FFN; out = h + ffn : 16 rows per block ----------
__global__ __launch_bounds__(256) void k_ffn(
  const float* __restrict__ xp, const float* __restrict__ ctxb,
  const float* __restrict__ g2, const float* __restrict__ b2v,
  const float* __restrict__ W1, const float* __restrict__ bb1,
  const float* __restrict__ W2, const float* __restrict__ bb2,
  float* __restrict__ out)
{
  const int R = 16, P = 20;
  __shared__ float hrow[R][DOUTC];
  __shared__ float hn[DOUTC*P];
  __shared__ float hid[256*P];
  int tid=threadIdx.x, w=tid>>6, lane=tid&63;
  int row0 = blockIdx.x*R;
  for (int i=tid;i<R*DOUTC;i+=256){
    int r=i>>7, c=i&127;
    size_t gi = (size_t)(row0+r)*DOUTC + c;
    hrow[r][c] = xp[gi] + ctxb[gi];
  }
  __syncthreads();
  float ga=g2[lane], gb=g2[lane+64], ba=b2v[lane], bbx=b2v[lane+64];
  for (int r=w; r<R; r+=4){
    float a = hrow[r][lane], c = hrow[r][lane+64];
    float s = wsum(a+c);
    float q = wsum(a*a+c*c);
    float mean = s*(1.f/DOUTC);
    float var  = q*(1.f/DOUTC)-mean*mean;
    float rstd = rsqrtf(var+1e-5f);
    hn[lane*P + r]      = (a-mean)*rstd*ga + ba;
    hn[(lane+64)*P + r] = (c-mean)*rstd*gb + bbx;
  }
  __syncthreads();
  {
    int j=tid;
    float acc[R];
    float bj = bb1[j];
#pragma unroll
    for (int r=0;r<R;++r) acc[r]=bj;
    for (int i=0;i<DOUTC;++i){
      float wv = W1[i*256 + j];
      const float4* xa = (const float4*)&hn[i*P];
      float4 a=xa[0], b=xa[1], c=xa[2], d=xa[3];
      acc[0]+=a.x*wv;  acc[1]+=a.y*wv;  acc[2]+=a.z*wv;  acc[3]+=a.w*wv;
      acc[4]+=b.x*wv;  acc[5]+=b.y*wv;  acc[6]+=b.z*wv;  acc[7]+=b.w*wv;
      acc[8]+=c.x*wv;  acc[9]+=c.y*wv;  acc[10]+=c.z*wv; acc[11]+=c.w*wv;
      acc[12]+=d.x*wv; acc[13]+=d.y*wv; acc[14]+=d.z*wv; acc[15]+=d.w*wv;
    }
#pragma unroll
    for (int r=0;r<R;++r) hid[j*P+r] = fmaxf(acc[r],0.f);
  }
  __syncthreads();
  {
    int j2 = tid&127, r0 = (tid>>7)*8;
    float acc[8];
#pragma unroll
    for (int r=0;r<8;++r) acc[r]=0.f;
    for (int i=0;i<256;++i){
      float wv = W2[i*DOUTC + j2];
      const float4* xa = (const float4*)&hid[i*P + r0];
      float4 a=xa[0], b=xa[1];
      acc[0]+=a.x*wv; acc[1]+=a.y*wv; acc[2]+=a.z*wv; acc[3]+=a.w*wv;
      acc[4]+=b.x*wv; acc[5]+=b.y*wv; acc[6]+=b.z*wv; acc[7]+=b.w*wv;
    }
    float bj = bb2[j2];
#pragma unroll
    for (int r=0;r<8;++r)
      out[(size_t)(row0+r0+r)*DOUTC + j2] = hrow[r0+r][j2] + acc[r] + bj;
  }
}

extern "C" void kernel_launch(void* const* d_in, const int* in_sizes, int n_in,
                              void* d_out, int out_size, void* d_ws, size_t ws_size,
                              hipStream_t stream)
{
  const float* x     = (const float*)d_in[0];
  const int*   adj   = (const int*)  d_in[1];
  const float* ea    = (const float*)d_in[2];
  const float* ln1_g = (const float*)d_in[3];
  const float* ln1_b = (const float*)d_in[4];
  const float* Wp    = (const float*)d_in[5];
  const float* bp    = (const float*)d_in[6];
  const float* eln_g = (const float*)d_in[7];
  const float* eln_b = (const float*)d_in[8];
  const float* We1   = (const float*)d_in[9];
  const float* be1   = (const float*)d_in[10];
  const float* We2   = (const float*)d_in[11];
  const float* be2   = (const float*)d_in[12];
  const float* Wq    = (const float*)d_in[13];
  const float* Wk    = (const float*)d_in[14];
  const float* Wv    = (const float*)d_in[15];
  const float* ffW1  = (const float*)d_in[16];
  const float* ffb1  = (const float*)d_in[17];
  const float* ffW2  = (const float*)d_in[18];
  const float* ffb2  = (const float*)d_in[19];
  const float* ln2_g = (const float*)d_in[20];
  const float* ln2_b = (const float*)d_in[21];
  float* out = (float*)d_out;

  char* ws = (char*)d_ws;
  float*    xp  = (float*)(ws);                       // 2MB
  float*    ctx = (float*)(ws + ((size_t)2<<20));     // 2MB
  _Float16* Qh  = (_Float16*)(ws + ((size_t)4<<20));  // 1MB
  _Float16* Kh  = (_Float16*)(ws + ((size_t)5<<20));  // 1MB
  _Float16* Vtb = (_Float16*)(ws + ((size_t)6<<20));  // 1MB  [b,h,d,n]

  k_proj<<<(BB*NN)/8, 128, 0, stream>>>(x, ln1_g, ln1_b, Wp, bp, Wq, Wk, Wv, xp, Qh, Kh, Vtb);
  k_fused<<<BB*(NN/4), 256, 0, stream>>>(ea, adj, eln_g, eln_b, We1, be1, We2, be2,
                                         Qh, Kh, Vtb, ctx);
  k_ffn<<<(BB*NN)/16, 256, 0, stream>>>(xp, ctx, ln2_g, ln2_b, ffW1, ffb1, ffW2, ffb2, out);
}

// Round 7
// 189.061 us; speedup vs baseline: 1.5035x; 1.5035x over previous
//
#include <hip/hip_runtime.h>
#include <hip/hip_bf16.h>

#define BB 8
#define NN 512
#define DINC 128
#define DOUTC 128
#define HHC 8
#define EEC 16
#define DHC 16

typedef _Float16 h4 __attribute__((ext_vector_type(4)));
typedef float f32x4 __attribute__((ext_vector_type(4)));

__device__ __forceinline__ float wsum(float v){
#pragma unroll
  for (int o=1;o<64;o<<=1) v += __shfl_xor(v,o);
  return v;
}

// ---------- LN1 + Wp + Q/K/V projections: 8 rows per 128-thread block ----------
// Q,K written [b,h,n,d]; V written TRANSPOSED [b,h,d,n] for the fused kernel.
__global__ __launch_bounds__(128) void k_proj(
    const float* __restrict__ x,
    const float* __restrict__ g1, const float* __restrict__ b1,
    const float* __restrict__ Wp, const float* __restrict__ bp,
    const float* __restrict__ Wq, const float* __restrict__ Wk, const float* __restrict__ Wv,
    float* __restrict__ xp, _Float16* __restrict__ Qh, _Float16* __restrict__ Kh, _Float16* __restrict__ Vt)
{
  const int R = 8, P = 12;
  __shared__ float xln[DINC*P];
  __shared__ float xps[DINC*P];
  __shared__ float part[2][R][2];
  int tid = threadIdx.x, w = tid>>6, lane = tid&63;
  int row0 = blockIdx.x * R;
  float v[R];
#pragma unroll
  for (int r=0;r<R;++r) v[r] = x[(size_t)(row0+r)*DINC + tid];
  float gg = g1[tid], bbv = b1[tid];
#pragma unroll
  for (int r=0;r<R;++r){
    float s = wsum(v[r]);
    float q = wsum(v[r]*v[r]);
    if (lane==0){ part[w][r][0]=s; part[w][r][1]=q; }
  }
  __syncthreads();
#pragma unroll
  for (int r=0;r<R;++r){
    float s = part[0][r][0]+part[1][r][0];
    float q = part[0][r][1]+part[1][r][1];
    float mean = s*(1.f/DINC);
    float var  = q*(1.f/DINC) - mean*mean;
    float rstd = rsqrtf(var + 1e-5f);
    xln[tid*P + r] = (v[r]-mean)*rstd*gg + bbv;
  }
  __syncthreads();
  int j = tid;
  float acc[R];
  {
    float bj = bp[j];
#pragma unroll
    for (int r=0;r<R;++r) acc[r]=bj;
    for (int i=0;i<DINC;++i){
      float wv = Wp[i*DOUTC + j];
      const float4* xa = (const float4*)&xln[i*P];
      float4 a = xa[0], b = xa[1];
      acc[0]+=a.x*wv; acc[1]+=a.y*wv; acc[2]+=a.z*wv; acc[3]+=a.w*wv;
      acc[4]+=b.x*wv; acc[5]+=b.y*wv; acc[6]+=b.z*wv; acc[7]+=b.w*wv;
    }
#pragma unroll
    for (int r=0;r<R;++r){
      xps[j*P + r] = acc[r];
      xp[(size_t)(row0+r)*DOUTC + j] = acc[r];
    }
  }
  __syncthreads();
  const float* Ws[3] = {Wq, Wk, Wv};
#pragma unroll
  for (int mmat=0;mmat<3;++mmat){
    const float* W = Ws[mmat];
#pragma unroll
    for (int r=0;r<R;++r) acc[r]=0.f;
    for (int i=0;i<DINC;++i){
      float wv = W[i*DOUTC + j];
      const float4* xa = (const float4*)&xps[i*P];
      float4 a = xa[0], b = xa[1];
      acc[0]+=a.x*wv; acc[1]+=a.y*wv; acc[2]+=a.z*wv; acc[3]+=a.w*wv;
      acc[4]+=b.x*wv; acc[5]+=b.y*wv; acc[6]+=b.z*wv; acc[7]+=b.w*wv;
    }
    int h = j>>4, d = j&15;
#pragma unroll
    for (int r=0;r<R;++r){
      int row = row0+r; int bidx = row>>9, n = row&(NN-1);
      if (mmat==0)      Qh[(((size_t)bidx*HHC + h)*NN + n)*DHC + d] = (_Float16)acc[r];
      else if (mmat==1) Kh[(((size_t)bidx*HHC + h)*NN + n)*DHC + d] = (_Float16)acc[r];
      else              Vt[(((size_t)bidx*HHC + h)*DHC + d)*NN + n] = (_Float16)acc[r];
    }
  }
}

// ---------- FUSED edge-MLP + attention, v4 ----------
// v3 but WITHOUT the __launch_bounds__ min-waves arg: (256,4) capped the
// allocator at 64 VGPRs (m69: waves halve at 64) and spilled the whole
// working set to scratch (R5: 138MB, R6: 215MB of VMEM writes). Default
// bounds -> ~104 VGPRs, still 4 waves/SIMD, zero spill (R4 proved this).
__global__ __launch_bounds__(256) void k_fused(
  const float* __restrict__ ea, const int* __restrict__ adj,
  const float* __restrict__ eg, const float* __restrict__ ebi,
  const float* __restrict__ We1, const float* __restrict__ be1,
  const float* __restrict__ We2, const float* __restrict__ be2,
  const _Float16* __restrict__ Qh, const _Float16* __restrict__ Kh,
  const _Float16* __restrict__ Vt, float* __restrict__ ctxb)
{
  __shared__ _Float16 biasL[2][8][4][72];      // [buf][h][n][m pad72] 9.2KB
  __shared__ unsigned long long mrow[4][8];

  int tid = threadIdx.x, w = tid>>6, lane = tid&63;
  int c = lane&15, g = lane>>4;
  int blk = blockIdx.x;
  int b = blk>>7, tile = blk&127;
  int n0 = tile*4;

  // adjacency bitmask (+self loop) for the 4 rows
#pragma unroll
  for (int k=0;k<4;++k){
    int row = n0+k;
#pragma unroll
    for (int half=0;half<2;++half){
      int col = half*256 + tid;
      int val = (adj[((size_t)b*NN + row)*NN + col] != 0) || (col == row);
      unsigned long long bal = __ballot(val);
      if (lane==0) mrow[k][half*4 + w] = bal;
    }
  }

  // MLP weight A-fragments (transposed-layer trick, verified R3/R4)
  h4 w1a,w1b,w2a,w2b;
#pragma unroll
  for (int j=0;j<4;++j){
    w1a[j] = (_Float16)We1[(4*g+j)*32 + c];
    w1b[j] = (_Float16)We1[(4*g+j)*32 + 16 + c];
    w2a[j] = (_Float16)((c<8)? We2[(4*g+j)*HHC + c] : 0.f);
    w2b[j] = (_Float16)((c<8)? We2[(16+4*g+j)*HHC + c] : 0.f);
  }
  float4 b1a = *(const float4*)(be1 + 4*g);
  float4 b1b = *(const float4*)(be1 + 16 + 4*g);
  float4 b2r = *(const float4*)(be2 + (g&1)*4);
  float4 G4  = *(const float4*)(eg  + 4*g);
  float4 Bv4 = *(const float4*)(ebi + 4*g);

  // Q B-fragments for this wave's two heads (4 valid rows, c&3; cols 4-15 dup)
  int h0 = w, h1 = w+4;
  h4 qf0 = *(const h4*)(Qh + (((size_t)b*HHC + h0)*NN + n0 + (c&3))*DHC + 4*g);
  h4 qf1 = *(const h4*)(Qh + (((size_t)b*HHC + h1)*NN + n0 + (c&3))*DHC + 4*g);

  const float* eaRow = ea + (((size_t)b*NN + n0 + w)*NN)*EEC;   // wave's MLP row

  f32x4 acc0 = {0.f,0.f,0.f,0.f}, acc1 = {0.f,0.f,0.f,0.f};
  float rs0 = 0.f, rs1 = 0.f;

  float4 erA0,erA1,erA2,erA3, erB0,erB1,erB2,erB3;   // static double-buffer
  erA0 = *(const float4*)(eaRow + (size_t)( 0*16 + c)*EEC + 4*g);
  erA1 = *(const float4*)(eaRow + (size_t)( 1*16 + c)*EEC + 4*g);
  erA2 = *(const float4*)(eaRow + (size_t)( 2*16 + c)*EEC + 4*g);
  erA3 = *(const float4*)(eaRow + (size_t)( 3*16 + c)*EEC + 4*g);

  __syncthreads();   // mrow visible

  // ---- MLP for chunk ch from 4 static float4s -> biasL[ch&1]
  auto MLP = [&](int ch, float4 e0, float4 e1, float4 e2, float4 e3){
    int buf = ch & 1;
    unsigned long long wm = mrow[w][ch];
    float4 ee[4] = {e0,e1,e2,e3};        // static-indexed below (unrolled)
#pragma unroll
    for (int mg=0;mg<4;++mg){
      float4 v = ee[mg];
      float s = v.x+v.y+v.z+v.w;
      float q = v.x*v.x+v.y*v.y+v.z*v.z+v.w*v.w;
      s += __shfl_xor(s,16); s += __shfl_xor(s,32);
      q += __shfl_xor(q,16); q += __shfl_xor(q,32);
      float mean = s*(1.f/EEC);
      float var  = q*(1.f/EEC) - mean*mean;
      float rstd = rsqrtf(var + 1e-5f);
      h4 ef;
      ef[0]=(_Float16)((v.x-mean)*rstd*G4.x + Bv4.x);
      ef[1]=(_Float16)((v.y-mean)*rstd*G4.y + Bv4.y);
      ef[2]=(_Float16)((v.z-mean)*rstd*G4.z + Bv4.z);
      ef[3]=(_Float16)((v.w-mean)*rstd*G4.w + Bv4.w);
      f32x4 d1a = {b1a.x,b1a.y,b1a.z,b1a.w};
      f32x4 d1b = {b1b.x,b1b.y,b1b.z,b1b.w};
      d1a = __builtin_amdgcn_mfma_f32_16x16x16f16(w1a, ef, d1a, 0,0,0);
      d1b = __builtin_amdgcn_mfma_f32_16x16x16f16(w1b, ef, d1b, 0,0,0);
      h4 hfa,hfb;
#pragma unroll
      for (int r=0;r<4;++r){
        hfa[r]=(_Float16)fmaxf(d1a[r],0.f);
        hfb[r]=(_Float16)fmaxf(d1b[r],0.f);
      }
      f32x4 d2 = {0.f,0.f,0.f,0.f};
      d2 = __builtin_amdgcn_mfma_f32_16x16x16f16(w2a, hfa, d2, 0,0,0);
      d2 = __builtin_amdgcn_mfma_f32_16x16x16f16(w2b, hfb, d2, 0,0,0);
      if (g<2){
#pragma unroll
        for (int r=0;r<4;++r){
          float y = d2[r] + ((const float*)&b2r)[r];
          y = fminf(fmaxf(2.f*y,-30.f),30.f);
          float ex = __expf(y);
          float t = (ex-1.f)/(ex+1.f);                 // tanh
          bool ok = (wm >> (mg*16+c)) & 1ull;
          biasL[buf][4*g+r][w][mg*16+c] = ok ? (_Float16)(5.f*t) : (_Float16)(-30000.f);
        }
      }
    }
  };

  // ---- attention on chunk ch, heads h0,h1 (accumulates acc0/1, rs0/1)
  auto ATTN = [&](int ch){
#pragma unroll
    for (int hh=0; hh<2; ++hh){
      int head = hh ? h1 : h0;
      h4 qf = hh ? qf1 : qf0;
      const _Float16* Kb = Kh + (((size_t)b*HHC + head)*NN + ch*64)*DHC;
      const _Float16* Vb = Vt + (((size_t)b*HHC + head)*DHC + c)*NN + ch*64;
      const _Float16* bb = &biasL[ch&1][head][c&3][0];
      f32x4 a = hh ? acc1 : acc0;
      float rs = 0.f;
#pragma unroll
      for (int t=0;t<4;++t){
        h4 kf = *(const h4*)(Kb + (16*t + c)*DHC + 4*g);
        f32x4 zero = {0.f,0.f,0.f,0.f};
        f32x4 d = __builtin_amdgcn_mfma_f32_16x16x16f16(kf, qf, zero, 0,0,0);
        h4 e4 = *(const h4*)(bb + 16*t + 4*g);
        h4 pa;
#pragma unroll
        for (int r=0;r<4;++r){
          float sv = d[r]*0.25f + (float)e4[r];
          sv = fmaxf(sv,0.f) + 0.2f*fminf(sv,0.f);     // LeakyReLU(0.2)
          float p = __expf(sv - 6.f);
          rs += p;
          pa[r] = (_Float16)p;
        }
        h4 vf = *(const h4*)(Vb + 16*t + 4*g);
        a = __builtin_amdgcn_mfma_f32_16x16x16f16(pa, vf, a, 0,0,0);
      }
      if (hh){ acc1 = a; rs1 += rs; } else { acc0 = a; rs0 += rs; }
    }
  };

  MLP(0, erA0, erA1, erA2, erA3);        // produce chunk 0

#pragma unroll
  for (int cc=0; cc<4; ++cc){
    { // even chunk ch=2cc: consume A, prefetch+produce B
      const int ch = 2*cc;
      erB0 = *(const float4*)(eaRow + (size_t)((ch+1)*64 +  0 + c)*EEC + 4*g);
      erB1 = *(const float4*)(eaRow + (size_t)((ch+1)*64 + 16 + c)*EEC + 4*g);
      erB2 = *(const float4*)(eaRow + (size_t)((ch+1)*64 + 32 + c)*EEC + 4*g);
      erB3 = *(const float4*)(eaRow + (size_t)((ch+1)*64 + 48 + c)*EEC + 4*g);
      __syncthreads();                   // biasL[ch&1] ready
      ATTN(ch);
      MLP(ch+1, erB0, erB1, erB2, erB3);
    }
    { // odd chunk ch=2cc+1: consume B, prefetch+produce A
      const int ch = 2*cc+1;
      if (ch<7){
        erA0 = *(const float4*)(eaRow + (size_t)((ch+1)*64 +  0 + c)*EEC + 4*g);
        erA1 = *(const float4*)(eaRow + (size_t)((ch+1)*64 + 16 + c)*EEC + 4*g);
        erA2 = *(const float4*)(eaRow + (size_t)((ch+1)*64 + 32 + c)*EEC + 4*g);
        erA3 = *(const float4*)(eaRow + (size_t)((ch+1)*64 + 48 + c)*EEC + 4*g);
      }
      __syncthreads();                   // biasL[ch&1] ready
      ATTN(ch);
      if (ch<7) MLP(ch+1, erA0, erA1, erA2, erA3);
    }
  }

  // rowsum: reduce over g-copies ONLY (c-copies hold identical sums)
  rs0 += __shfl_xor(rs0,16); rs0 += __shfl_xor(rs0,32);
  rs1 += __shfl_xor(rs1,16); rs1 += __shfl_xor(rs1,32);
  float s0r[4], s1r[4];
#pragma unroll
  for (int r=0;r<4;++r){ s0r[r]=__shfl(rs0,r); s1r[r]=__shfl(rs1,r); }

  // ctx D-layout: lane(c,g) holds rows n=4g+r (valid g==0), d=c
  if (g==0){
#pragma unroll
    for (int r=0;r<4;++r){
      size_t rowoff = ((size_t)b*NN + n0 + r)*DOUTC;
      ctxb[rowoff + h0*DHC + c] = acc0[r]/s0r[r];
      ctxb[rowoff + h1*DHC + c] = acc1[r]/s1r[r];
    }
  }
}

// ---------- h = xp+ctx; LN2; FFN; out = h + ffn : 16 rows per block ----------
__global__ __launch_bounds__(256) void k_ffn(
  const float* __restrict__ xp, const float* __restrict__ ctxb,
  const float* __restrict__ g2, const float* __restrict__ b2v,
  const float* __restrict__ W1, const float* __restrict__ bb1,
  const float* __restrict__ W2, const float* __restrict__ bb2,
  float* __restrict__ out)
{
  const int R = 16, P = 20;
  __shared__ float hrow[R][DOUTC];
  __shared__ float hn[DOUTC*P];
  __shared__ float hid[256*P];
  int tid=threadIdx.x, w=tid>>6, lane=tid&63;
  int row0 = blockIdx.x*R;
  for (int i=tid;i<R*DOUTC;i+=256){
    int r=i>>7, c=i&127;
    size_t gi = (size_t)(row0+r)*DOUTC + c;
    hrow[r][c] = xp[gi] + ctxb[gi];
  }
  __syncthreads();
  float ga=g2[lane], gb=g2[lane+64], ba=b2v[lane], bbx=b2v[lane+64];
  for (int r=w; r<R; r+=4){
    float a = hrow[r][lane], c = hrow[r][lane+64];
    float s = wsum(a+c);
    float q = wsum(a*a+c*c);
    float mean = s*(1.f/DOUTC);
    float var  = q*(1.f/DOUTC)-mean*mean;
    float rstd = rsqrtf(var+1e-5f);
    hn[lane*P + r]      = (a-mean)*rstd*ga + ba;
    hn[(lane+64)*P + r] = (c-mean)*rstd*gb + bbx;
  }
  __syncthreads();
  {
    int j=tid;
    float acc[R];
    float bj = bb1[j];
#pragma unroll
    for (int r=0;r<R;++r) acc[r]=bj;
    for (int i=0;i<DOUTC;++i){
      float wv = W1[i*256 + j];
      const float4* xa = (const float4*)&hn[i*P];
      float4 a=xa[0], b=xa[1], c=xa[2], d=xa[3];
      acc[0]+=a.x*wv;  acc[1]+=a.y*wv;  acc[2]+=a.z*wv;  acc[3]+=a.w*wv;
      acc[4]+=b.x*wv;  acc[5]+=b.y*wv;  acc[6]+=b.z*wv;  acc[7]+=b.w*wv;
      acc[8]+=c.x*wv;  acc[9]+=c.y*wv;  acc[10]+=c.z*wv; acc[11]+=c.w*wv;
      acc[12]+=d.x*wv; acc[13]+=d.y*wv; acc[14]+=d.z*wv; acc[15]+=d.w*wv;
    }
#pragma unroll
    for (int r=0;r<R;++r) hid[j*P+r] = fmaxf(acc[r],0.f);
  }
  __syncthreads();
  {
    int j2 = tid&127, r0 = (tid>>7)*8;
    float acc[8];
#pragma unroll
    for (int r=0;r<8;++r) acc[r]=0.f;
    for (int i=0;i<256;++i){
      float wv = W2[i*DOUTC + j2];
      const float4* xa = (const float4*)&hid[i*P + r0];
      float4 a=xa[0], b=xa[1];
      acc[0]+=a.x*wv; acc[1]+=a.y*wv; acc[2]+=a.z*wv; acc[3]+=a.w*wv;
      acc[4]+=b.x*wv; acc[5]+=b.y*wv; acc[6]+=b.z*wv; acc[7]+=b.w*wv;
    }
    float bj = bb2[j2];
#pragma unroll
    for (int r=0;r<8;++r)
      out[(size_t)(row0+r0+r)*DOUTC + j2] = hrow[r0+r][j2] + acc[r] + bj;
  }
}

extern "C" void kernel_launch(void* const* d_in, const int* in_sizes, int n_in,
                              void* d_out, int out_size, void* d_ws, size_t ws_size,
                              hipStream_t stream)
{
  const float* x     = (const float*)d_in[0];
  const int*   adj   = (const int*)  d_in[1];
  const float* ea    = (const float*)d_in[2];
  const float* ln1_g = (const float*)d_in[3];
  const float* ln1_b = (const float*)d_in[4];
  const float* Wp    = (const float*)d_in[5];
  const float* bp    = (const float*)d_in[6];
  const float* eln_g = (const float*)d_in[7];
  const float* eln_b = (const float*)d_in[8];
  const float* We1   = (const float*)d_in[9];
  const float* be1   = (const float*)d_in[10];
  const float* We2   = (const float*)d_in[11];
  const float* be2   = (const float*)d_in[12];
  const float* Wq    = (const float*)d_in[13];
  const float* Wk    = (const float*)d_in[14];
  const float* Wv    = (const float*)d_in[15];
  const float* ffW1  = (const float*)d_in[16];
  const float* ffb1  = (const float*)d_in[17];
  const float* ffW2  = (const float*)d_in[18];
  const float* ffb2  = (const float*)d_in[19];
  const float* ln2_g = (const float*)d_in[20];
  const float* ln2_b = (const float*)d_in[21];
  float* out = (float*)d_out;

  char* ws = (char*)d_ws;
  float*    xp  = (float*)(ws);                       // 2MB
  float*    ctx = (float*)(ws + ((size_t)2<<20));     // 2MB
  _Float16* Qh  = (_Float16*)(ws + ((size_t)4<<20));  // 1MB
  _Float16* Kh  = (_Float16*)(ws + ((size_t)5<<20));  // 1MB
  _Float16* Vtb = (_Float16*)(ws + ((size_t)6<<20));  // 1MB  [b,h,d,n]

  k_proj<<<(BB*NN)/8, 128, 0, stream>>>(x, ln1_g, ln1_b, Wp, bp, Wq, Wk, Wv, xp, Qh, Kh, Vtb);
  k_fused<<<BB*(NN/4), 256, 0, stream>>>(ea, adj, eln_g, eln_b, We1, be1, We2, be2,
                                         Qh, Kh, Vtb, ctx);
  k_ffn<<<(BB*NN)/16, 256, 0, stream>>>(xp, ctx, ln2_g, ln2_b, ffW1, ffb1, ffW2, ffb2, out);
}

// Round 8
// 114.619 us; speedup vs baseline: 2.4800x; 1.6495x over previous
//
#include <hip/hip_runtime.h>
#include <hip/hip_bf16.h>

#define BB 8
#define NN 512
#define DINC 128
#define DOUTC 128
#define HHC 8
#define EEC 16
#define DHC 16

typedef _Float16 h4 __attribute__((ext_vector_type(4)));
typedef float f32x4 __attribute__((ext_vector_type(4)));

__device__ __forceinline__ float wsum(float v){
#pragma unroll
  for (int o=1;o<64;o<<=1) v += __shfl_xor(v,o);
  return v;
}

// ---------- LN1 + Wp + Q/K/V projections: 8 rows per 128-thread block ----------
__global__ __launch_bounds__(128) void k_proj(
    const float* __restrict__ x,
    const float* __restrict__ g1, const float* __restrict__ b1,
    const float* __restrict__ Wp, const float* __restrict__ bp,
    const float* __restrict__ Wq, const float* __restrict__ Wk, const float* __restrict__ Wv,
    float* __restrict__ xp, _Float16* __restrict__ Qh, _Float16* __restrict__ Kh, _Float16* __restrict__ Vh)
{
  const int R = 8, P = 12;
  __shared__ float xln[DINC*P];
  __shared__ float xps[DINC*P];
  __shared__ float part[2][R][2];
  int tid = threadIdx.x, w = tid>>6, lane = tid&63;
  int row0 = blockIdx.x * R;
  float v[R];
#pragma unroll
  for (int r=0;r<R;++r) v[r] = x[(size_t)(row0+r)*DINC + tid];
  float gg = g1[tid], bbv = b1[tid];
#pragma unroll
  for (int r=0;r<R;++r){
    float s = wsum(v[r]);
    float q = wsum(v[r]*v[r]);
    if (lane==0){ part[w][r][0]=s; part[w][r][1]=q; }
  }
  __syncthreads();
#pragma unroll
  for (int r=0;r<R;++r){
    float s = part[0][r][0]+part[1][r][0];
    float q = part[0][r][1]+part[1][r][1];
    float mean = s*(1.f/DINC);
    float var  = q*(1.f/DINC) - mean*mean;
    float rstd = rsqrtf(var + 1e-5f);
    xln[tid*P + r] = (v[r]-mean)*rstd*gg + bbv;
  }
  __syncthreads();
  int j = tid;
  float acc[R];
  {
    float bj = bp[j];
#pragma unroll
    for (int r=0;r<R;++r) acc[r]=bj;
    for (int i=0;i<DINC;++i){
      float wv = Wp[i*DOUTC + j];
      const float4* xa = (const float4*)&xln[i*P];
      float4 a = xa[0], b = xa[1];
      acc[0]+=a.x*wv; acc[1]+=a.y*wv; acc[2]+=a.z*wv; acc[3]+=a.w*wv;
      acc[4]+=b.x*wv; acc[5]+=b.y*wv; acc[6]+=b.z*wv; acc[7]+=b.w*wv;
    }
#pragma unroll
    for (int r=0;r<R;++r){
      xps[j*P + r] = acc[r];
      xp[(size_t)(row0+r)*DOUTC + j] = acc[r];
    }
  }
  __syncthreads();
  const float* Ws[3] = {Wq, Wk, Wv};
  _Float16* Os[3] = {Qh, Kh, Vh};
#pragma unroll
  for (int mmat=0;mmat<3;++mmat){
    const float* W = Ws[mmat];
#pragma unroll
    for (int r=0;r<R;++r) acc[r]=0.f;
    for (int i=0;i<DINC;++i){
      float wv = W[i*DOUTC + j];
      const float4* xa = (const float4*)&xps[i*P];
      float4 a = xa[0], b = xa[1];
      acc[0]+=a.x*wv; acc[1]+=a.y*wv; acc[2]+=a.z*wv; acc[3]+=a.w*wv;
      acc[4]+=b.x*wv; acc[5]+=b.y*wv; acc[6]+=b.z*wv; acc[7]+=b.w*wv;
    }
    int h = j>>4, d = j&15;
    _Float16* O = Os[mmat];
#pragma unroll
    for (int r=0;r<R;++r){
      int row = row0+r; int bidx = row>>9, n = row&(NN-1);
      O[(((size_t)bidx*HHC + h)*NN + n)*DHC + d] = (_Float16)acc[r];
    }
  }
}

// ---------- edge-bias MLP v3: one WAVE per 64-edge group, no block barrier ----------
// grid 8192 x 256thr = 32768 independent waves (8/SIMD). Transposed-MFMA MLP
// (verified R3/R4). Mask baked (-30000). Per-wave LDS transpose -> 8x128B stores.
__global__ __launch_bounds__(256) void k_edge(
  const float* __restrict__ ea, const int* __restrict__ adj,
  const float* __restrict__ eg, const float* __restrict__ ebi,
  const float* __restrict__ We1, const float* __restrict__ be1,
  const float* __restrict__ We2, const float* __restrict__ be2,
  _Float16* __restrict__ ebias)
{
  __shared__ _Float16 stage[4][8][72];      // per-wave [h][64m pad72] transpose buf
  int tid = threadIdx.x, w = tid>>6, lane = tid&63;
  int c = lane&15, g = lane>>4;
  int blk = blockIdx.x;
  int b = blk>>10, rem = blk&1023;
  int n = rem>>1, half = rem&1;
  int m0 = half*256 + w*64;

  // adjacency bits for this wave's 64 columns (+ self loop)
  int adjv = adj[((size_t)(b*NN)+n)*NN + m0 + lane];
  unsigned long long wm = __ballot(adjv!=0 || (m0+lane)==n);

  // MLP weight A-fragments (transposed-layer trick)
  h4 w1a,w1b,w2a,w2b;
#pragma unroll
  for (int j=0;j<4;++j){
    w1a[j] = (_Float16)We1[(4*g+j)*32 + c];
    w1b[j] = (_Float16)We1[(4*g+j)*32 + 16 + c];
    w2a[j] = (_Float16)((c<8)? We2[(4*g+j)*HHC + c] : 0.f);
    w2b[j] = (_Float16)((c<8)? We2[(16+4*g+j)*HHC + c] : 0.f);
  }
  float4 b1a = *(const float4*)(be1 + 4*g);
  float4 b1b = *(const float4*)(be1 + 16 + 4*g);
  float4 b2r = *(const float4*)(be2 + (g&1)*4);
  float4 G4  = *(const float4*)(eg  + 4*g);
  float4 Bv4 = *(const float4*)(ebi + 4*g);

  const float* eaRow = ea + ((size_t)(b*NN)+n)*NN*EEC;
  // all 4 group loads upfront (independent)
  float4 e0 = *(const float4*)(eaRow + (size_t)(m0 +  0 + c)*EEC + 4*g);
  float4 e1 = *(const float4*)(eaRow + (size_t)(m0 + 16 + c)*EEC + 4*g);
  float4 e2 = *(const float4*)(eaRow + (size_t)(m0 + 32 + c)*EEC + 4*g);
  float4 e3 = *(const float4*)(eaRow + (size_t)(m0 + 48 + c)*EEC + 4*g);
  float4 ee[4] = {e0,e1,e2,e3};            // static-indexed in unrolled loop

#pragma unroll
  for (int mg=0;mg<4;++mg){
    float4 v = ee[mg];
    float s = v.x+v.y+v.z+v.w;
    float q = v.x*v.x+v.y*v.y+v.z*v.z+v.w*v.w;
    s += __shfl_xor(s,16); s += __shfl_xor(s,32);
    q += __shfl_xor(q,16); q += __shfl_xor(q,32);
    float mean = s*(1.f/EEC);
    float var  = q*(1.f/EEC) - mean*mean;
    float rstd = rsqrtf(var + 1e-5f);
    h4 ef;
    ef[0]=(_Float16)((v.x-mean)*rstd*G4.x + Bv4.x);
    ef[1]=(_Float16)((v.y-mean)*rstd*G4.y + Bv4.y);
    ef[2]=(_Float16)((v.z-mean)*rstd*G4.z + Bv4.z);
    ef[3]=(_Float16)((v.w-mean)*rstd*G4.w + Bv4.w);
    f32x4 d1a = {b1a.x,b1a.y,b1a.z,b1a.w};
    f32x4 d1b = {b1b.x,b1b.y,b1b.z,b1b.w};
    d1a = __builtin_amdgcn_mfma_f32_16x16x16f16(w1a, ef, d1a, 0,0,0);
    d1b = __builtin_amdgcn_mfma_f32_16x16x16f16(w1b, ef, d1b, 0,0,0);
    h4 hfa,hfb;
#pragma unroll
    for (int r=0;r<4;++r){
      hfa[r]=(_Float16)fmaxf(d1a[r],0.f);
      hfb[r]=(_Float16)fmaxf(d1b[r],0.f);
    }
    f32x4 d2 = {0.f,0.f,0.f,0.f};
    d2 = __builtin_amdgcn_mfma_f32_16x16x16f16(w2a, hfa, d2, 0,0,0);
    d2 = __builtin_amdgcn_mfma_f32_16x16x16f16(w2b, hfb, d2, 0,0,0);
    if (g<2){
#pragma unroll
      for (int r=0;r<4;++r){
        float y = d2[r] + ((const float*)&b2r)[r];
        y = fminf(fmaxf(2.f*y,-30.f),30.f);
        float ex = __expf(y);
        float t = (ex-1.f)/(ex+1.f);         // tanh
        bool ok = (wm >> (mg*16+c)) & 1ull;
        stage[w][4*g+r][mg*16+c] = ok ? (_Float16)(5.f*t) : (_Float16)(-30000.f);
      }
    }
  }
  // wave-local transpose readback: lane -> (h = lane>>3, m8 = lane&7), 16B each
  int h = lane>>3, m8 = lane&7;
  float4 val = *(const float4*)&stage[w][h][m8*8];   // compiler inserts lgkmcnt
  *(float4*)(ebias + (((size_t)b*HHC + h)*NN + n)*NN + m0 + m8*8) = val;
}

// ---------- MFMA attention (R3-verified): block=(b,h,64-row tile), 4 waves ----------
__global__ __launch_bounds__(256) void k_attn(
  const _Float16* __restrict__ Qh, const _Float16* __restrict__ Kh, const _Float16* __restrict__ Vh,
  const _Float16* __restrict__ eb, float* __restrict__ ctxb)
{
  __shared__ _Float16 Klds[NN*DHC];      // 16KB row-major [m][d]
  __shared__ _Float16 Vt[DHC*520];       // 16.25KB transposed [d][m], pad 520
  int tid = threadIdx.x;
  int bh   = blockIdx.x >> 3;
  int tile = blockIdx.x & 7;
  const _Float16* Kg = Kh + (size_t)bh*NN*DHC;
  const _Float16* Vg = Vh + (size_t)bh*NN*DHC;
  {
    const float4* src = (const float4*)Kg;
    float4* dst = (float4*)Klds;
#pragma unroll
    for (int i=tid;i<1024;i+=256) dst[i]=src[i];
  }
  {
#pragma unroll
    for (int i=tid;i<1024;i+=256){
      int m = i>>1, hf = i&1;
      float4 v4 = *(const float4*)(Vg + (size_t)m*DHC + hf*8);
      const _Float16* hh = (const _Float16*)&v4;
#pragma unroll
      for (int jj=0;jj<8;++jj) Vt[(hf*8+jj)*520 + m] = hh[jj];
    }
  }
  __syncthreads();

  int w = tid>>6, lane = tid&63;
  int c = lane&15, g = lane>>4;
  int n0 = tile*64 + w*16;

  h4 qf = *(const h4*)(Qh + ((size_t)bh*NN + n0 + c)*DHC + 4*g);
  const _Float16* ebw = eb + ((size_t)bh*NN + n0 + c)*NN + 4*g;

  float s[32][4];
  float mx = -3.0e38f;
  f32x4 zero = {0.f,0.f,0.f,0.f};
#pragma unroll
  for (int t=0;t<32;++t){
    h4 kf = *(const h4*)(Klds + (16*t + c)*DHC + 4*g);
    f32x4 d = __builtin_amdgcn_mfma_f32_16x16x16f16(kf, qf, zero, 0, 0, 0);
    h4 e4 = *(const h4*)(ebw + 16*t);
#pragma unroll
    for (int r=0;r<4;++r){
      float sv = d[r]*0.25f + (float)e4[r];
      sv = fmaxf(sv,0.f) + 0.2f*fminf(sv,0.f);
      s[t][r] = sv;
      mx = fmaxf(mx, sv);
    }
  }
  mx = fmaxf(mx, __shfl_xor(mx,16));
  mx = fmaxf(mx, __shfl_xor(mx,32));

  float rowsum = 0.f;
  f32x4 acc = zero;
#pragma unroll
  for (int t=0;t<32;++t){
    float p0=__expf(s[t][0]-mx), p1=__expf(s[t][1]-mx);
    float p2=__expf(s[t][2]-mx), p3=__expf(s[t][3]-mx);
    rowsum += (p0+p1)+(p2+p3);
    h4 pa; pa[0]=(_Float16)p0; pa[1]=(_Float16)p1; pa[2]=(_Float16)p2; pa[3]=(_Float16)p3;
    h4 vf = *(const h4*)(Vt + c*520 + 16*t + 4*g);
    acc = __builtin_amdgcn_mfma_f32_16x16x16f16(pa, vf, acc, 0, 0, 0);
  }
  rowsum += __shfl_xor(rowsum,16);
  rowsum += __shfl_xor(rowsum,32);

  int b = bh>>3, h = bh&7;
#pragma unroll
  for (int r=0;r<4;++r){
    float sr = __shfl(rowsum, g*16 + 4*g + r);
    ctxb[((size_t)b*NN + n0 + 4*g + r)*DOUTC + h*DHC + c] = acc[r]/sr;
  }
}

// ---------- h = xp+ctx; LN2; FFN; out = h + ffn : 16 rows per block ----------
__global__ __launch_bounds__(256) void k_ffn(
  const float* __restrict__ xp, const float* __restrict__ ctxb,
  const float* __restrict__ g2, const float* __restrict__ b2v,
  const float* __restrict__ W1, const float* __restrict__ bb1,
  const float* __restrict__ W2, const float* __restrict__ bb2,
  float* __restrict__ out)
{
  const int R = 16, P = 20;
  __shared__ float hrow[R][DOUTC];
  __shared__ float hn[DOUTC*P];
  __shared__ float hid[256*P];
  int tid=threadIdx.x, w=tid>>6, lane=tid&63;
  int row0 = blockIdx.x*R;
  for (int i=tid;i<R*DOUTC;i+=256){
    int r=i>>7, c=i&127;
    size_t gi = (size_t)(row0+r)*DOUTC + c;
    hrow[r][c] = xp[gi] + ctxb[gi];
  }
  __syncthreads();
  float ga=g2[lane], gb=g2[lane+64], ba=b2v[lane], bbx=b2v[lane+64];
  for (int r=w; r<R; r+=4){
    float a = hrow[r][lane], c = hrow[r][lane+64];
    float s = wsum(a+c);
    float q = wsum(a*a+c*c);
    float mean = s*(1.f/DOUTC);
    float var  = q*(1.f/DOUTC)-mean*mean;
    float rstd = rsqrtf(var+1e-5f);
    hn[lane*P + r]      = (a-mean)*rstd*ga + ba;
    hn[(lane+64)*P + r] = (c-mean)*rstd*gb + bbx;
  }
  __syncthreads();
  {
    int j=tid;
    float acc[R];
    float bj = bb1[j];
#pragma unroll
    for (int r=0;r<R;++r) acc[r]=bj;
    for (int i=0;i<DOUTC;++i){
      float wv = W1[i*256 + j];
      const float4* xa = (const float4*)&hn[i*P];
      float4 a=xa[0], b=xa[1], c=xa[2], d=xa[3];
      acc[0]+=a.x*wv;  acc[1]+=a.y*wv;  acc[2]+=a.z*wv;  acc[3]+=a.w*wv;
      acc[4]+=b.x*wv;  acc[5]+=b.y*wv;  acc[6]+=b.z*wv;  acc[7]+=b.w*wv;
      acc[8]+=c.x*wv;  acc[9]+=c.y*wv;  acc[10]+=c.z*wv; acc[11]+=c.w*wv;
      acc[12]+=d.x*wv; acc[13]+=d.y*wv; acc[14]+=d.z*wv; acc[15]+=d.w*wv;
    }
#pragma unroll
    for (int r=0;r<R;++r) hid[j*P+r] = fmaxf(acc[r],0.f);
  }
  __syncthreads();
  {
    int j2 = tid&127, r0 = (tid>>7)*8;
    float acc[8];
#pragma unroll
    for (int r=0;r<8;++r) acc[r]=0.f;
    for (int i=0;i<256;++i){
      float wv = W2[i*DOUTC + j2];
      const float4* xa = (const float4*)&hid[i*P + r0];
      float4 a=xa[0], b=xa[1];
      acc[0]+=a.x*wv; acc[1]+=a.y*wv; acc[2]+=a.z*wv; acc[3]+=a.w*wv;
      acc[4]+=b.x*wv; acc[5]+=b.y*wv; acc[6]+=b.z*wv; acc[7]+=b.w*wv;
    }
    float bj = bb2[j2];
#pragma unroll
    for (int r=0;r<8;++r)
      out[(size_t)(row0+r0+r)*DOUTC + j2] = hrow[r0+r][j2] + acc[r] + bj;
  }
}

extern "C" void kernel_launch(void* const* d_in, const int* in_sizes, int n_in,
                              void* d_out, int out_size, void* d_ws, size_t ws_size,
                              hipStream_t stream)
{
  const float* x     = (const float*)d_in[0];
  const int*   adj   = (const int*)  d_in[1];
  const float* ea    = (const float*)d_in[2];
  const float* ln1_g = (const float*)d_in[3];
  const float* ln1_b = (const float*)d_in[4];
  const float* Wp    = (const float*)d_in[5];
  const float* bp    = (const float*)d_in[6];
  const float* eln_g = (const float*)d_in[7];
  const float* eln_b = (const float*)d_in[8];
  const float* We1   = (const float*)d_in[9];
  const float* be1   = (const float*)d_in[10];
  const float* We2   = (const float*)d_in[11];
  const float* be2   = (const float*)d_in[12];
  const float* Wq    = (const float*)d_in[13];
  const float* Wk    = (const float*)d_in[14];
  const float* Wv    = (const float*)d_in[15];
  const float* ffW1  = (const float*)d_in[16];
  const float* ffb1  = (const float*)d_in[17];
  const float* ffW2  = (const float*)d_in[18];
  const float* ffb2  = (const float*)d_in[19];
  const float* ln2_g = (const float*)d_in[20];
  const float* ln2_b = (const float*)d_in[21];
  float* out = (float*)d_out;

  char* ws = (char*)d_ws;
  float*    xp  = (float*)(ws);                       // 2MB
  float*    ctx = (float*)(ws + ((size_t)2<<20));     // 2MB
  _Float16* Qh  = (_Float16*)(ws + ((size_t)4<<20));  // 1MB
  _Float16* Kh  = (_Float16*)(ws + ((size_t)5<<20));  // 1MB
  _Float16* Vh  = (_Float16*)(ws + ((size_t)6<<20));  // 1MB
  _Float16* ebf = (_Float16*)(ws + ((size_t)7<<20));  // 32MB [B,H,N,N] f16 (mask baked)

  k_proj<<<(BB*NN)/8, 128, 0, stream>>>(x, ln1_g, ln1_b, Wp, bp, Wq, Wk, Wv, xp, Qh, Kh, Vh);
  k_edge<<<BB*NN*2, 256, 0, stream>>>(ea, adj, eln_g, eln_b, We1, be1, We2, be2, ebf);
  k_attn<<<BB*HHC*8, 256, 0, stream>>>(Qh, Kh, Vh, ebf, ctx);
  k_ffn<<<(BB*NN)/16, 256, 0, stream>>>(xp, ctx, ln2_g, ln2_b, ffW1, ffb1, ffW2, ffb2, out);
}

// Round 9
// 104.600 us; speedup vs baseline: 2.7176x; 1.0958x over previous
//
#include <hip/hip_runtime.h>
#include <hip/hip_bf16.h>

#define BB 8
#define NN 512
#define DINC 128
#define DOUTC 128
#define HHC 8
#define EEC 16
#define DHC 16

typedef _Float16 h4 __attribute__((ext_vector_type(4)));
typedef float f32x4 __attribute__((ext_vector_type(4)));

__device__ __forceinline__ float wsum(float v){
#pragma unroll
  for (int o=1;o<64;o<<=1) v += __shfl_xor(v,o);
  return v;
}

// ---------- LN1 + Wp + Q/K/V projections: 8 rows per 128-thread block ----------
__global__ __launch_bounds__(128) void k_proj(
    const float* __restrict__ x,
    const float* __restrict__ g1, const float* __restrict__ b1,
    const float* __restrict__ Wp, const float* __restrict__ bp,
    const float* __restrict__ Wq, const float* __restrict__ Wk, const float* __restrict__ Wv,
    float* __restrict__ xp, _Float16* __restrict__ Qh, _Float16* __restrict__ Kh, _Float16* __restrict__ Vh)
{
  const int R = 8, P = 12;
  __shared__ float xln[DINC*P];
  __shared__ float xps[DINC*P];
  __shared__ float part[2][R][2];
  int tid = threadIdx.x, w = tid>>6, lane = tid&63;
  int row0 = blockIdx.x * R;
  float v[R];
#pragma unroll
  for (int r=0;r<R;++r) v[r] = x[(size_t)(row0+r)*DINC + tid];
  float gg = g1[tid], bbv = b1[tid];
#pragma unroll
  for (int r=0;r<R;++r){
    float s = wsum(v[r]);
    float q = wsum(v[r]*v[r]);
    if (lane==0){ part[w][r][0]=s; part[w][r][1]=q; }
  }
  __syncthreads();
#pragma unroll
  for (int r=0;r<R;++r){
    float s = part[0][r][0]+part[1][r][0];
    float q = part[0][r][1]+part[1][r][1];
    float mean = s*(1.f/DINC);
    float var  = q*(1.f/DINC) - mean*mean;
    float rstd = rsqrtf(var + 1e-5f);
    xln[tid*P + r] = (v[r]-mean)*rstd*gg + bbv;
  }
  __syncthreads();
  int j = tid;
  float acc[R];
  {
    float bj = bp[j];
#pragma unroll
    for (int r=0;r<R;++r) acc[r]=bj;
    for (int i=0;i<DINC;++i){
      float wv = Wp[i*DOUTC + j];
      const float4* xa = (const float4*)&xln[i*P];
      float4 a = xa[0], b = xa[1];
      acc[0]+=a.x*wv; acc[1]+=a.y*wv; acc[2]+=a.z*wv; acc[3]+=a.w*wv;
      acc[4]+=b.x*wv; acc[5]+=b.y*wv; acc[6]+=b.z*wv; acc[7]+=b.w*wv;
    }
#pragma unroll
    for (int r=0;r<R;++r){
      xps[j*P + r] = acc[r];
      xp[(size_t)(row0+r)*DOUTC + j] = acc[r];
    }
  }
  __syncthreads();
  const float* Ws[3] = {Wq, Wk, Wv};
  _Float16* Os[3] = {Qh, Kh, Vh};
#pragma unroll
  for (int mmat=0;mmat<3;++mmat){
    const float* W = Ws[mmat];
#pragma unroll
    for (int r=0;r<R;++r) acc[r]=0.f;
    for (int i=0;i<DINC;++i){
      float wv = W[i*DOUTC + j];
      const float4* xa = (const float4*)&xps[i*P];
      float4 a = xa[0], b = xa[1];
      acc[0]+=a.x*wv; acc[1]+=a.y*wv; acc[2]+=a.z*wv; acc[3]+=a.w*wv;
      acc[4]+=b.x*wv; acc[5]+=b.y*wv; acc[6]+=b.z*wv; acc[7]+=b.w*wv;
    }
    int h = j>>4, d = j&15;
    _Float16* O = Os[mmat];
#pragma unroll
    for (int r=0;r<R;++r){
      int row = row0+r; int bidx = row>>9, n = row&(NN-1);
      O[(((size_t)bidx*HHC + h)*NN + n)*DHC + d] = (_Float16)acc[r];
    }
  }
}

// ---------- edge-bias MLP (unchanged from R8) ----------
__global__ __launch_bounds__(256) void k_edge(
  const float* __restrict__ ea, const int* __restrict__ adj,
  const float* __restrict__ eg, const float* __restrict__ ebi,
  const float* __restrict__ We1, const float* __restrict__ be1,
  const float* __restrict__ We2, const float* __restrict__ be2,
  _Float16* __restrict__ ebias)
{
  __shared__ _Float16 stage[4][8][72];
  int tid = threadIdx.x, w = tid>>6, lane = tid&63;
  int c = lane&15, g = lane>>4;
  int blk = blockIdx.x;
  int b = blk>>10, rem = blk&1023;
  int n = rem>>1, half = rem&1;
  int m0 = half*256 + w*64;

  int adjv = adj[((size_t)(b*NN)+n)*NN + m0 + lane];
  unsigned long long wm = __ballot(adjv!=0 || (m0+lane)==n);

  h4 w1a,w1b,w2a,w2b;
#pragma unroll
  for (int j=0;j<4;++j){
    w1a[j] = (_Float16)We1[(4*g+j)*32 + c];
    w1b[j] = (_Float16)We1[(4*g+j)*32 + 16 + c];
    w2a[j] = (_Float16)((c<8)? We2[(4*g+j)*HHC + c] : 0.f);
    w2b[j] = (_Float16)((c<8)? We2[(16+4*g+j)*HHC + c] : 0.f);
  }
  float4 b1a = *(const float4*)(be1 + 4*g);
  float4 b1b = *(const float4*)(be1 + 16 + 4*g);
  float4 b2r = *(const float4*)(be2 + (g&1)*4);
  float4 G4  = *(const float4*)(eg  + 4*g);
  float4 Bv4 = *(const float4*)(ebi + 4*g);

  const float* eaRow = ea + ((size_t)(b*NN)+n)*NN*EEC;
  float4 e0 = *(const float4*)(eaRow + (size_t)(m0 +  0 + c)*EEC + 4*g);
  float4 e1 = *(const float4*)(eaRow + (size_t)(m0 + 16 + c)*EEC + 4*g);
  float4 e2 = *(const float4*)(eaRow + (size_t)(m0 + 32 + c)*EEC + 4*g);
  float4 e3 = *(const float4*)(eaRow + (size_t)(m0 + 48 + c)*EEC + 4*g);
  float4 ee[4] = {e0,e1,e2,e3};

#pragma unroll
  for (int mg=0;mg<4;++mg){
    float4 v = ee[mg];
    float s = v.x+v.y+v.z+v.w;
    float q = v.x*v.x+v.y*v.y+v.z*v.z+v.w*v.w;
    s += __shfl_xor(s,16); s += __shfl_xor(s,32);
    q += __shfl_xor(q,16); q += __shfl_xor(q,32);
    float mean = s*(1.f/EEC);
    float var  = q*(1.f/EEC) - mean*mean;
    float rstd = rsqrtf(var + 1e-5f);
    h4 ef;
    ef[0]=(_Float16)((v.x-mean)*rstd*G4.x + Bv4.x);
    ef[1]=(_Float16)((v.y-mean)*rstd*G4.y + Bv4.y);
    ef[2]=(_Float16)((v.z-mean)*rstd*G4.z + Bv4.z);
    ef[3]=(_Float16)((v.w-mean)*rstd*G4.w + Bv4.w);
    f32x4 d1a = {b1a.x,b1a.y,b1a.z,b1a.w};
    f32x4 d1b = {b1b.x,b1b.y,b1b.z,b1b.w};
    d1a = __builtin_amdgcn_mfma_f32_16x16x16f16(w1a, ef, d1a, 0,0,0);
    d1b = __builtin_amdgcn_mfma_f32_16x16x16f16(w1b, ef, d1b, 0,0,0);
    h4 hfa,hfb;
#pragma unroll
    for (int r=0;r<4;++r){
      hfa[r]=(_Float16)fmaxf(d1a[r],0.f);
      hfb[r]=(_Float16)fmaxf(d1b[r],0.f);
    }
    f32x4 d2 = {0.f,0.f,0.f,0.f};
    d2 = __builtin_amdgcn_mfma_f32_16x16x16f16(w2a, hfa, d2, 0,0,0);
    d2 = __builtin_amdgcn_mfma_f32_16x16x16f16(w2b, hfb, d2, 0,0,0);
    if (g<2){
#pragma unroll
      for (int r=0;r<4;++r){
        float y = d2[r] + ((const float*)&b2r)[r];
        y = fminf(fmaxf(2.f*y,-30.f),30.f);
        float ex = __expf(y);
        float t = (ex-1.f)/(ex+1.f);
        bool ok = (wm >> (mg*16+c)) & 1ull;
        stage[w][4*g+r][mg*16+c] = ok ? (_Float16)(5.f*t) : (_Float16)(-30000.f);
      }
    }
  }
  int h = lane>>3, m8 = lane&7;
  float4 val = *(const float4*)&stage[w][h][m8*8];
  *(float4*)(ebias + (((size_t)b*HHC + h)*NN + n)*NN + m0 + m8*8) = val;
}

// ---------- MFMA attention v2: single-pass fixed-shift softmax ----------
// exp(s-6), no max reduction, no s[32][4] storage (was 128 VGPRs -> 2 waves/SIMD).
// Numerics verified in R4/R7 (same absmax as max-sub version): scores bounded,
// masked = -30000 -> exp underflows to 0, diagonal keeps rowsum > 0.
__global__ __launch_bounds__(256) void k_attn(
  const _Float16* __restrict__ Qh, const _Float16* __restrict__ Kh, const _Float16* __restrict__ Vh,
  const _Float16* __restrict__ eb, float* __restrict__ ctxb)
{
  __shared__ _Float16 Klds[NN*DHC];      // 16KB row-major [m][d]
  __shared__ _Float16 Vt[DHC*520];       // 16.25KB transposed [d][m], pad 520
  int tid = threadIdx.x;
  int bh   = blockIdx.x >> 3;
  int tile = blockIdx.x & 7;
  const _Float16* Kg = Kh + (size_t)bh*NN*DHC;
  const _Float16* Vg = Vh + (size_t)bh*NN*DHC;
  {
    const float4* src = (const float4*)Kg;
    float4* dst = (float4*)Klds;
#pragma unroll
    for (int i=tid;i<1024;i+=256) dst[i]=src[i];
  }
  {
#pragma unroll
    for (int i=tid;i<1024;i+=256){
      int m = i>>1, hf = i&1;
      float4 v4 = *(const float4*)(Vg + (size_t)m*DHC + hf*8);
      const _Float16* hh = (const _Float16*)&v4;
#pragma unroll
      for (int jj=0;jj<8;++jj) Vt[(hf*8+jj)*520 + m] = hh[jj];
    }
  }
  __syncthreads();

  int w = tid>>6, lane = tid&63;
  int c = lane&15, g = lane>>4;
  int n0 = tile*64 + w*16;

  h4 qf = *(const h4*)(Qh + ((size_t)bh*NN + n0 + c)*DHC + 4*g);
  const _Float16* ebw = eb + ((size_t)bh*NN + n0 + c)*NN + 4*g;

  f32x4 zero = {0.f,0.f,0.f,0.f};
  f32x4 acc = zero;
  float rowsum = 0.f;
#pragma unroll
  for (int t=0;t<32;++t){
    h4 kf = *(const h4*)(Klds + (16*t + c)*DHC + 4*g);
    f32x4 d = __builtin_amdgcn_mfma_f32_16x16x16f16(kf, qf, zero, 0, 0, 0);
    h4 e4 = *(const h4*)(ebw + 16*t);
    h4 pa;
#pragma unroll
    for (int r=0;r<4;++r){
      float sv = d[r]*0.25f + (float)e4[r];
      sv = fmaxf(sv,0.f) + 0.2f*fminf(sv,0.f);   // LeakyReLU(0.2)
      float p = __expf(sv - 6.f);                // fixed shift, no max-sub
      rowsum += p;
      pa[r] = (_Float16)p;
    }
    h4 vf = *(const h4*)(Vt + c*520 + 16*t + 4*g);
    acc = __builtin_amdgcn_mfma_f32_16x16x16f16(pa, vf, acc, 0, 0, 0);
  }
  rowsum += __shfl_xor(rowsum,16);
  rowsum += __shfl_xor(rowsum,32);

  int b = bh>>3, h = bh&7;
#pragma unroll
  for (int r=0;r<4;++r){
    float sr = __shfl(rowsum, g*16 + 4*g + r);
    ctxb[((size_t)b*NN + n0 + 4*g + r)*DOUTC + h*DHC + c] = acc[r]/sr;
  }
}

// ---------- FFN v2: MFMA, transposed-chaining (k_edge-verified trick) ----------
// Block = 16 rows, 4 waves. Wave w owns hidden tiles 4w..4w+3 (layer 1), then
// computes layer-2 partials over its 4 tiles; 4-way reduce via LDS.
__global__ __launch_bounds__(256) void k_ffn(
  const float* __restrict__ xp, const float* __restrict__ ctxb,
  const float* __restrict__ g2, const float* __restrict__ b2v,
  const float* __restrict__ W1, const float* __restrict__ bb1,
  const float* __restrict__ W2, const float* __restrict__ bb2,
  float* __restrict__ out)
{
  __shared__ float    hrow[16][DOUTC];       // 8KB residual
  __shared__ _Float16 hn[16][136];           // 4.25KB LN2 output (pad 136)
  __shared__ float    part[4][8][16][16];    // 32KB layer-2 partials

  int tid = threadIdx.x, w = tid>>6, lane = tid&63;
  int c = lane&15, g = lane>>4;
  int n0 = blockIdx.x * 16;

  // ---- h = xp+ctx; LN2 -> hn (f16). Wave w handles rows {w, w+4, w+8, w+12}.
  float ga=g2[lane], gb=g2[lane+64], ba=b2v[lane], bbx=b2v[lane+64];
#pragma unroll
  for (int rr=0;rr<4;++rr){
    int r = w + rr*4;
    size_t gi = (size_t)(n0+r)*DOUTC + lane;
    float a  = xp[gi]    + ctxb[gi];
    float cc = xp[gi+64] + ctxb[gi+64];
    hrow[r][lane] = a; hrow[r][lane+64] = cc;
    float s = wsum(a+cc);
    float q = wsum(a*a+cc*cc);
    float mean = s*(1.f/DOUTC);
    float var  = q*(1.f/DOUTC) - mean*mean;
    float rstd = rsqrtf(var + 1e-5f);
    hn[r][lane]    = (_Float16)((a -mean)*rstd*ga + ba);
    hn[r][lane+64] = (_Float16)((cc-mean)*rstd*gb + bbx);
  }

  // ---- layer-1 weight fragments: A[m=hid c][k=4g+j], hid tile ht=4w+t
  h4 w1f[4][8];                              // [t][kt], all static-indexed
#pragma unroll
  for (int t=0;t<4;++t){
    int ht = 4*w + t;
#pragma unroll
    for (int kt=0;kt<8;++kt){
      h4 f;
#pragma unroll
      for (int j=0;j<4;++j)
        f[j] = (_Float16)W1[(size_t)(16*kt + 4*g + j)*256 + 16*ht + c];
      w1f[t][kt] = f;
    }
  }

  __syncthreads();                           // hn ready

  // ---- layer 1: Hid^T[16ht+4g+r][row c] = sum_kt W1^T-frag x hn-frag + b1
  f32x4 D1[4];
#pragma unroll
  for (int t=0;t<4;++t){
    float4 bi = *(const float4*)(bb1 + 16*(4*w+t) + 4*g);
    D1[t][0]=bi.x; D1[t][1]=bi.y; D1[t][2]=bi.z; D1[t][3]=bi.w;
  }
#pragma unroll
  for (int kt=0;kt<8;++kt){
    h4 hb = *(const h4*)&hn[c][16*kt + 4*g];  // B[k=4g+j][n=row c]
#pragma unroll
    for (int t=0;t<4;++t)
      D1[t] = __builtin_amdgcn_mfma_f32_16x16x16f16(w1f[t][kt], hb, D1[t], 0,0,0);
  }
  h4 hidB[4];                                // relu; D r-regs == next B j-slots
#pragma unroll
  for (int t=0;t<4;++t)
#pragma unroll
    for (int r=0;r<4;++r)
      hidB[t][r] = (_Float16)fmaxf(D1[t][r], 0.f);

  // ---- layer-2 weight fragments: A[m=outcol c][k=hid 4g+j], k-tile = 4w+t
  h4 w2f[8][4];                              // [ot][t]
#pragma unroll
  for (int ot=0;ot<8;++ot){
#pragma unroll
    for (int t=0;t<4;++t){
      h4 f;
#pragma unroll
      for (int j=0;j<4;++j)
        f[j] = (_Float16)W2[(size_t)(16*(4*w+t) + 4*g + j)*128 + 16*ot + c];
      w2f[ot][t] = f;
    }
  }

  // ---- layer 2 partial over this wave's 4 hid tiles
  f32x4 D2[8];
#pragma unroll
  for (int ot=0;ot<8;++ot){ D2[ot][0]=0.f; D2[ot][1]=0.f; D2[ot][2]=0.f; D2[ot][3]=0.f; }
#pragma unroll
  for (int t=0;t<4;++t)
#pragma unroll
    for (int ot=0;ot<8;++ot)
      D2[ot] = __builtin_amdgcn_mfma_f32_16x16x16f16(w2f[ot][t], hidB[t], D2[ot], 0,0,0);

  // ---- stash partials; 4-way reduce; epilogue
#pragma unroll
  for (int ot=0;ot<8;++ot)
#pragma unroll
    for (int r=0;r<4;++r)
      part[w][ot][4*g+r][c] = D2[ot][r];
  __syncthreads();

#pragma unroll
  for (int i=tid;i<2048;i+=256){
    int n = i>>7, col = i&127;
    int ot = col>>4, m = col&15;
    float v = part[0][ot][m][n] + part[1][ot][m][n]
            + part[2][ot][m][n] + part[3][ot][m][n];
    out[(size_t)(n0+n)*DOUTC + col] = hrow[n][col] + v + bb2[col];
  }
}

extern "C" void kernel_launch(void* const* d_in, const int* in_sizes, int n_in,
                              void* d_out, int out_size, void* d_ws, size_t ws_size,
                              hipStream_t stream)
{
  const float* x     = (const float*)d_in[0];
  const int*   adj   = (const int*)  d_in[1];
  const float* ea    = (const float*)d_in[2];
  const float* ln1_g = (const float*)d_in[3];
  const float* ln1_b = (const float*)d_in[4];
  const float* Wp    = (const float*)d_in[5];
  const float* bp    = (const float*)d_in[6];
  const float* eln_g = (const float*)d_in[7];
  const float* eln_b = (const float*)d_in[8];
  const float* We1   = (const float*)d_in[9];
  const float* be1   = (const float*)d_in[10];
  const float* We2   = (const float*)d_in[11];
  const float* be2   = (const float*)d_in[12];
  const float* Wq    = (const float*)d_in[13];
  const float* Wk    = (const float*)d_in[14];
  const float* Wv    = (const float*)d_in[15];
  const float* ffW1  = (const float*)d_in[16];
  const float* ffb1  = (const float*)d_in[17];
  const float* ffW2  = (const float*)d_in[18];
  const float* ffb2  = (const float*)d_in[19];
  const float* ln2_g = (const float*)d_in[20];
  const float* ln2_b = (const float*)d_in[21];
  float* out = (float*)d_out;

  char* ws = (char*)d_ws;
  float*    xp  = (float*)(ws);                       // 2MB
  float*    ctx = (float*)(ws + ((size_t)2<<20));     // 2MB
  _Float16* Qh  = (_Float16*)(ws + ((size_t)4<<20));  // 1MB
  _Float16* Kh  = (_Float16*)(ws + ((size_t)5<<20));  // 1MB
  _Float16* Vh  = (_Float16*)(ws + ((size_t)6<<20));  // 1MB
  _Float16* ebf = (_Float16*)(ws + ((size_t)7<<20));  // 32MB [B,H,N,N] f16 (mask baked)

  k_proj<<<(BB*NN)/8, 128, 0, stream>>>(x, ln1_g, ln1_b, Wp, bp, Wq, Wk, Wv, xp, Qh, Kh, Vh);
  k_edge<<<BB*NN*2, 256, 0, stream>>>(ea, adj, eln_g, eln_b, We1, be1, We2, be2, ebf);
  k_attn<<<BB*HHC*8, 256, 0, stream>>>(Qh, Kh, Vh, ebf, ctx);
  k_ffn<<<(BB*NN)/16, 256, 0, stream>>>(xp, ctx, ln2_g, ln2_b, ffW1, ffb1, ffW2, ffb2, out);
}

// Round 10
// 84.145 us; speedup vs baseline: 3.3782x; 1.2431x over previous
//
#include <hip/hip_runtime.h>
#include <hip/hip_bf16.h>

#define BB 8
#define NN 512
#define DINC 128
#define DOUTC 128
#define HHC 8
#define EEC 16
#define DHC 16

typedef _Float16 h4 __attribute__((ext_vector_type(4)));
typedef float f32x4 __attribute__((ext_vector_type(4)));

__device__ __forceinline__ float wsum(float v){
#pragma unroll
  for (int o=1;o<64;o<<=1) v += __shfl_xor(v,o);
  return v;
}

// ---------- LN1 + Wp + Q/K/V projections: 8 rows per 128-thread block ----------
__global__ __launch_bounds__(128) void k_proj(
    const float* __restrict__ x,
    const float* __restrict__ g1, const float* __restrict__ b1,
    const float* __restrict__ Wp, const float* __restrict__ bp,
    const float* __restrict__ Wq, const float* __restrict__ Wk, const float* __restrict__ Wv,
    float* __restrict__ xp, _Float16* __restrict__ Qh, _Float16* __restrict__ Kh, _Float16* __restrict__ Vh)
{
  const int R = 8, P = 12;
  __shared__ float xln[DINC*P];
  __shared__ float xps[DINC*P];
  __shared__ float part[2][R][2];
  int tid = threadIdx.x, w = tid>>6, lane = tid&63;
  int row0 = blockIdx.x * R;
  float v[R];
#pragma unroll
  for (int r=0;r<R;++r) v[r] = x[(size_t)(row0+r)*DINC + tid];
  float gg = g1[tid], bbv = b1[tid];
#pragma unroll
  for (int r=0;r<R;++r){
    float s = wsum(v[r]);
    float q = wsum(v[r]*v[r]);
    if (lane==0){ part[w][r][0]=s; part[w][r][1]=q; }
  }
  __syncthreads();
#pragma unroll
  for (int r=0;r<R;++r){
    float s = part[0][r][0]+part[1][r][0];
    float q = part[0][r][1]+part[1][r][1];
    float mean = s*(1.f/DINC);
    float var  = q*(1.f/DINC) - mean*mean;
    float rstd = rsqrtf(var + 1e-5f);
    xln[tid*P + r] = (v[r]-mean)*rstd*gg + bbv;
  }
  __syncthreads();
  int j = tid;
  float acc[R];
  {
    float bj = bp[j];
#pragma unroll
    for (int r=0;r<R;++r) acc[r]=bj;
    for (int i=0;i<DINC;++i){
      float wv = Wp[i*DOUTC + j];
      const float4* xa = (const float4*)&xln[i*P];
      float4 a = xa[0], b = xa[1];
      acc[0]+=a.x*wv; acc[1]+=a.y*wv; acc[2]+=a.z*wv; acc[3]+=a.w*wv;
      acc[4]+=b.x*wv; acc[5]+=b.y*wv; acc[6]+=b.z*wv; acc[7]+=b.w*wv;
    }
#pragma unroll
    for (int r=0;r<R;++r){
      xps[j*P + r] = acc[r];
      xp[(size_t)(row0+r)*DOUTC + j] = acc[r];
    }
  }
  __syncthreads();
  const float* Ws[3] = {Wq, Wk, Wv};
  _Float16* Os[3] = {Qh, Kh, Vh};
#pragma unroll
  for (int mmat=0;mmat<3;++mmat){
    const float* W = Ws[mmat];
#pragma unroll
    for (int r=0;r<R;++r) acc[r]=0.f;
    for (int i=0;i<DINC;++i){
      float wv = W[i*DOUTC + j];
      const float4* xa = (const float4*)&xps[i*P];
      float4 a = xa[0], b = xa[1];
      acc[0]+=a.x*wv; acc[1]+=a.y*wv; acc[2]+=a.z*wv; acc[3]+=a.w*wv;
      acc[4]+=b.x*wv; acc[5]+=b.y*wv; acc[6]+=b.z*wv; acc[7]+=b.w*wv;
    }
    int h = j>>4, d = j&15;
    _Float16* O = Os[mmat];
#pragma unroll
    for (int r=0;r<R;++r){
      int row = row0+r; int bidx = row>>9, n = row&(NN-1);
      O[(((size_t)bidx*HHC + h)*NN + n)*DHC + d] = (_Float16)acc[r];
    }
  }
}

// ---------- edge-bias MLP v4: per-row COMPACTION (skip ~50% masked edges) ----------
// Block = one (b,n) row, 4 waves. adj ballot -> u16 index list of unmasked cols;
// stage prefilled -30000; transposed-MFMA MLP (verified R3+) runs only over
// ceil(cnt/16) tiles; results scattered to original columns; coalesced writeout.
__global__ __launch_bounds__(256) void k_edge(
  const float* __restrict__ ea, const int* __restrict__ adj,
  const float* __restrict__ eg, const float* __restrict__ ebi,
  const float* __restrict__ We1, const float* __restrict__ be1,
  const float* __restrict__ We2, const float* __restrict__ be2,
  _Float16* __restrict__ ebias)
{
  __shared__ _Float16 stage[8][520];         // [h][512 pad520] 8.1KB
  __shared__ unsigned long long msk[8];
  __shared__ unsigned short idx16[512];
  __shared__ int cntS;

  int tid = threadIdx.x, w = tid>>6, lane = tid&63;
  int c = lane&15, g = lane>>4;
  int bn = blockIdx.x;
  int b = bn >> 9, n = bn & (NN-1);

  // ---- adjacency ballots: wave w covers chunks w and w+4
  const int* adjRow = adj + (size_t)bn*NN;
  int col1 = tid, col2 = tid + 256;
  int v1 = (adjRow[col1] != 0) || (col1 == n);
  int v2 = (adjRow[col2] != 0) || (col2 == n);
  unsigned long long b1m = __ballot(v1);
  unsigned long long b2m = __ballot(v2);
  if (lane==0){ msk[w] = b1m; msk[4+w] = b2m; }

  // MLP weight A-fragments (transposed-layer trick, verified R3/R4)
  h4 w1a,w1b,w2a,w2b;
#pragma unroll
  for (int j=0;j<4;++j){
    w1a[j] = (_Float16)We1[(4*g+j)*32 + c];
    w1b[j] = (_Float16)We1[(4*g+j)*32 + 16 + c];
    w2a[j] = (_Float16)((c<8)? We2[(4*g+j)*HHC + c] : 0.f);
    w2b[j] = (_Float16)((c<8)? We2[(16+4*g+j)*HHC + c] : 0.f);
  }
  float4 b1a = *(const float4*)(be1 + 4*g);
  float4 b1b = *(const float4*)(be1 + 16 + 4*g);
  float4 b2r = *(const float4*)(be2 + (g&1)*4);
  float4 G4  = *(const float4*)(eg  + 4*g);
  float4 Bv4 = *(const float4*)(ebi + 4*g);

  __syncthreads();

  // ---- per-thread prefix over the 8 chunk popcounts (uniform, cheap)
  int offs[8]; int cnt = 0;
#pragma unroll
  for (int k=0;k<8;++k){ offs[k] = cnt; cnt += __popcll(msk[k]); }
  if (tid==0) cntS = cnt;

  // ---- prefill stage with -30000 (masked default): 8*512 f16 = 8KB
  {
    _Float16 neg = (_Float16)(-30000.f);
    h4 negv; negv[0]=neg; negv[1]=neg; negv[2]=neg; negv[3]=neg;
#pragma unroll
    for (int i=tid;i<1024;i+=256){         // 1024 x 8B chunks
      int h = i>>7, m4 = i&127;
      *(h4*)&stage[h][m4*4] = negv;
    }
  }

  // ---- compaction: wave w compacts chunks w and w+4
  if (v1){
    int pos = offs[w]   + __popcll(msk[w]   & ((1ull<<lane)-1ull));
    idx16[pos] = (unsigned short)col1;
  }
  if (v2){
    int pos = offs[4+w] + __popcll(msk[4+w] & ((1ull<<lane)-1ull));
    idx16[pos] = (unsigned short)col2;
  }
  __syncthreads();

  cnt = cntS;
  int nt = (cnt + 15) >> 4;
  const float* eaRow = ea + (size_t)bn*NN*EEC;

  for (int t = w; t < nt; t += 4){
    int slot = 16*t + c;
    int sidx = slot < cnt ? slot : cnt-1;
    int idx  = idx16[sidx];                 // broadcast across g (same addr)
    float4 v = *(const float4*)(eaRow + (size_t)idx*EEC + 4*g);
    float s = v.x+v.y+v.z+v.w;
    float q = v.x*v.x+v.y*v.y+v.z*v.z+v.w*v.w;
    s += __shfl_xor(s,16); s += __shfl_xor(s,32);
    q += __shfl_xor(q,16); q += __shfl_xor(q,32);
    float mean = s*(1.f/EEC);
    float var  = q*(1.f/EEC) - mean*mean;
    float rstd = rsqrtf(var + 1e-5f);
    h4 ef;
    ef[0]=(_Float16)((v.x-mean)*rstd*G4.x + Bv4.x);
    ef[1]=(_Float16)((v.y-mean)*rstd*G4.y + Bv4.y);
    ef[2]=(_Float16)((v.z-mean)*rstd*G4.z + Bv4.z);
    ef[3]=(_Float16)((v.w-mean)*rstd*G4.w + Bv4.w);
    f32x4 d1a = {b1a.x,b1a.y,b1a.z,b1a.w};
    f32x4 d1b = {b1b.x,b1b.y,b1b.z,b1b.w};
    d1a = __builtin_amdgcn_mfma_f32_16x16x16f16(w1a, ef, d1a, 0,0,0);
    d1b = __builtin_amdgcn_mfma_f32_16x16x16f16(w1b, ef, d1b, 0,0,0);
    h4 hfa,hfb;
#pragma unroll
    for (int r=0;r<4;++r){
      hfa[r]=(_Float16)fmaxf(d1a[r],0.f);
      hfb[r]=(_Float16)fmaxf(d1b[r],0.f);
    }
    f32x4 d2 = {0.f,0.f,0.f,0.f};
    d2 = __builtin_amdgcn_mfma_f32_16x16x16f16(w2a, hfa, d2, 0,0,0);
    d2 = __builtin_amdgcn_mfma_f32_16x16x16f16(w2b, hfb, d2, 0,0,0);
    if (g<2 && slot<cnt){
#pragma unroll
      for (int r=0;r<4;++r){
        float y = d2[r] + ((const float*)&b2r)[r];
        y = fminf(fmaxf(2.f*y,-30.f),30.f);
        float ex = __expf(y);
        float t2 = (ex-1.f)/(ex+1.f);       // tanh
        stage[4*g+r][idx] = (_Float16)(5.f*t2);
      }
    }
  }
  __syncthreads();

  // ---- coalesced writeout: 8 head planes x 1KB
  size_t base = ((size_t)b*HHC)*NN*NN + (size_t)n*NN;
#pragma unroll
  for (int i=tid;i<512;i+=256){
    int h = i>>6, m8 = i&63;
    *(float4*)(ebias + base + (size_t)h*NN*NN + m8*8) =
        *(const float4*)&stage[h][m8*8];
  }
}

// ---------- MFMA attention (R9-verified): fixed-shift single-pass softmax ----------
__global__ __launch_bounds__(256) void k_attn(
  const _Float16* __restrict__ Qh, const _Float16* __restrict__ Kh, const _Float16* __restrict__ Vh,
  const _Float16* __restrict__ eb, float* __restrict__ ctxb)
{
  __shared__ _Float16 Klds[NN*DHC];
  __shared__ _Float16 Vt[DHC*520];
  int tid = threadIdx.x;
  int bh   = blockIdx.x >> 3;
  int tile = blockIdx.x & 7;
  const _Float16* Kg = Kh + (size_t)bh*NN*DHC;
  const _Float16* Vg = Vh + (size_t)bh*NN*DHC;
  {
    const float4* src = (const float4*)Kg;
    float4* dst = (float4*)Klds;
#pragma unroll
    for (int i=tid;i<1024;i+=256) dst[i]=src[i];
  }
  {
#pragma unroll
    for (int i=tid;i<1024;i+=256){
      int m = i>>1, hf = i&1;
      float4 v4 = *(const float4*)(Vg + (size_t)m*DHC + hf*8);
      const _Float16* hh = (const _Float16*)&v4;
#pragma unroll
      for (int jj=0;jj<8;++jj) Vt[(hf*8+jj)*520 + m] = hh[jj];
    }
  }
  __syncthreads();

  int w = tid>>6, lane = tid&63;
  int c = lane&15, g = lane>>4;
  int n0 = tile*64 + w*16;

  h4 qf = *(const h4*)(Qh + ((size_t)bh*NN + n0 + c)*DHC + 4*g);
  const _Float16* ebw = eb + ((size_t)bh*NN + n0 + c)*NN + 4*g;

  f32x4 zero = {0.f,0.f,0.f,0.f};
  f32x4 acc = zero;
  float rowsum = 0.f;
#pragma unroll
  for (int t=0;t<32;++t){
    h4 kf = *(const h4*)(Klds + (16*t + c)*DHC + 4*g);
    f32x4 d = __builtin_amdgcn_mfma_f32_16x16x16f16(kf, qf, zero, 0, 0, 0);
    h4 e4 = *(const h4*)(ebw + 16*t);
    h4 pa;
#pragma unroll
    for (int r=0;r<4;++r){
      float sv = d[r]*0.25f + (float)e4[r];
      sv = fmaxf(sv,0.f) + 0.2f*fminf(sv,0.f);
      float p = __expf(sv - 6.f);
      rowsum += p;
      pa[r] = (_Float16)p;
    }
    h4 vf = *(const h4*)(Vt + c*520 + 16*t + 4*g);
    acc = __builtin_amdgcn_mfma_f32_16x16x16f16(pa, vf, acc, 0, 0, 0);
  }
  rowsum += __shfl_xor(rowsum,16);
  rowsum += __shfl_xor(rowsum,32);

  int b = bh>>3, h = bh&7;
#pragma unroll
  for (int r=0;r<4;++r){
    float sr = __shfl(rowsum, g*16 + 4*g + r);
    ctxb[((size_t)b*NN + n0 + 4*g + r)*DOUTC + h*DHC + c] = acc[r]/sr;
  }
}

// ---------- FFN v3: MFMA with STREAMED weight fragments (low VGPR) ----------
__global__ __launch_bounds__(256) void k_ffn(
  const float* __restrict__ xp, const float* __restrict__ ctxb,
  const float* __restrict__ g2, const float* __restrict__ b2v,
  const float* __restrict__ W1, const float* __restrict__ bb1,
  const float* __restrict__ W2, const float* __restrict__ bb2,
  float* __restrict__ out)
{
  __shared__ float    hrow[16][DOUTC];       // 8KB residual
  __shared__ _Float16 hn[16][136];           // 4.25KB LN2 output
  __shared__ float    part[4][8][16][16];    // 32KB layer-2 partials

  int tid = threadIdx.x, w = tid>>6, lane = tid&63;
  int c = lane&15, g = lane>>4;
  int n0 = blockIdx.x * 16;

  float ga=g2[lane], gb=g2[lane+64], ba=b2v[lane], bbx=b2v[lane+64];
#pragma unroll
  for (int rr=0;rr<4;++rr){
    int r = w + rr*4;
    size_t gi = (size_t)(n0+r)*DOUTC + lane;
    float a  = xp[gi]    + ctxb[gi];
    float cc = xp[gi+64] + ctxb[gi+64];
    hrow[r][lane] = a; hrow[r][lane+64] = cc;
    float s = wsum(a+cc);
    float q = wsum(a*a+cc*cc);
    float mean = s*(1.f/DOUTC);
    float var  = q*(1.f/DOUTC) - mean*mean;
    float rstd = rsqrtf(var + 1e-5f);
    hn[r][lane]    = (_Float16)((a -mean)*rstd*ga + ba);
    hn[r][lane+64] = (_Float16)((cc-mean)*rstd*gb + bbx);
  }
  __syncthreads();

  // ---- layer 1, t-major with streamed w1 fragments
  h4 hidB[4];
#pragma unroll
  for (int t=0;t<4;++t){
    int ht = 4*w + t;
    float4 bi = *(const float4*)(bb1 + 16*ht + 4*g);
    f32x4 D1; D1[0]=bi.x; D1[1]=bi.y; D1[2]=bi.z; D1[3]=bi.w;
#pragma unroll
    for (int kt=0;kt<8;++kt){
      h4 f;
#pragma unroll
      for (int j=0;j<4;++j)
        f[j] = (_Float16)W1[(size_t)(16*kt + 4*g + j)*256 + 16*ht + c];
      h4 hb = *(const h4*)&hn[c][16*kt + 4*g];
      D1 = __builtin_amdgcn_mfma_f32_16x16x16f16(f, hb, D1, 0,0,0);
    }
#pragma unroll
    for (int r=0;r<4;++r) hidB[t][r] = (_Float16)fmaxf(D1[r], 0.f);
  }

  // ---- layer 2, ot-major write-through (only one accumulator live)
#pragma unroll
  for (int ot=0;ot<8;++ot){
    f32x4 d2 = {0.f,0.f,0.f,0.f};
#pragma unroll
    for (int t=0;t<4;++t){
      h4 f;
#pragma unroll
      for (int j=0;j<4;++j)
        f[j] = (_Float16)W2[(size_t)(16*(4*w+t) + 4*g + j)*128 + 16*ot + c];
      d2 = __builtin_amdgcn_mfma_f32_16x16x16f16(f, hidB[t], d2, 0,0,0);
    }
#pragma unroll
    for (int r=0;r<4;++r) part[w][ot][4*g+r][c] = d2[r];
  }
  __syncthreads();

#pragma unroll
  for (int i=tid;i<2048;i+=256){
    int n = i>>7, col = i&127;
    int ot = col>>4, m = col&15;
    float v = part[0][ot][m][n] + part[1][ot][m][n]
            + part[2][ot][m][n] + part[3][ot][m][n];
    out[(size_t)(n0+n)*DOUTC + col] = hrow[n][col] + v + bb2[col];
  }
}

extern "C" void kernel_launch(void* const* d_in, const int* in_sizes, int n_in,
                              void* d_out, int out_size, void* d_ws, size_t ws_size,
                              hipStream_t stream)
{
  const float* x     = (const float*)d_in[0];
  const int*   adj   = (const int*)  d_in[1];
  const float* ea    = (const float*)d_in[2];
  const float* ln1_g = (const float*)d_in[3];
  const float* ln1_b = (const float*)d_in[4];
  const float* Wp    = (const float*)d_in[5];
  const float* bp    = (const float*)d_in[6];
  const float* eln_g = (const float*)d_in[7];
  const float* eln_b = (const float*)d_in[8];
  const float* We1   = (const float*)d_in[9];
  const float* be1   = (const float*)d_in[10];
  const float* We2   = (const float*)d_in[11];
  const float* be2   = (const float*)d_in[12];
  const float* Wq    = (const float*)d_in[13];
  const float* Wk    = (const float*)d_in[14];
  const float* Wv    = (const float*)d_in[15];
  const float* ffW1  = (const float*)d_in[16];
  const float* ffb1  = (const float*)d_in[17];
  const float* ffW2  = (const float*)d_in[18];
  const float* ffb2  = (const float*)d_in[19];
  const float* ln2_g = (const float*)d_in[20];
  const float* ln2_b = (const float*)d_in[21];
  float* out = (float*)d_out;

  char* ws = (char*)d_ws;
  float*    xp  = (float*)(ws);                       // 2MB
  float*    ctx = (float*)(ws + ((size_t)2<<20));     // 2MB
  _Float16* Qh  = (_Float16*)(ws + ((size_t)4<<20));  // 1MB
  _Float16* Kh  = (_Float16*)(ws + ((size_t)5<<20));  // 1MB
  _Float16* Vh  = (_Float16*)(ws + ((size_t)6<<20));  // 1MB
  _Float16* ebf = (_Float16*)(ws + ((size_t)7<<20));  // 32MB [B,H,N,N] f16 (mask baked)

  k_proj<<<(BB*NN)/8, 128, 0, stream>>>(x, ln1_g, ln1_b, Wp, bp, Wq, Wk, Wv, xp, Qh, Kh, Vh);
  k_edge<<<BB*NN, 256, 0, stream>>>(ea, adj, eln_g, eln_b, We1, be1, We2, be2, ebf);
  k_attn<<<BB*HHC*8, 256, 0, stream>>>(Qh, Kh, Vh, ebf, ctx);
  k_ffn<<<(BB*NN)/16, 256, 0, stream>>>(xp, ctx, ln2_g, ln2_b, ffW1, ffb1, ffW2, ffb2, out);
}

// Round 11
// 79.881 us; speedup vs baseline: 3.5585x; 1.0534x over previous
//
#include <hip/hip_runtime.h>
#include <hip/hip_bf16.h>

#define BB 8
#define NN 512
#define DINC 128
#define DOUTC 128
#define HHC 8
#define EEC 16
#define DHC 16

typedef _Float16 h4 __attribute__((ext_vector_type(4)));
typedef float f32x4 __attribute__((ext_vector_type(4)));

__device__ __forceinline__ float wsum(float v){
#pragma unroll
  for (int o=1;o<64;o<<=1) v += __shfl_xor(v,o);
  return v;
}

// ---------- proj v2: LN1 + MFMA GEMMs (xp, then Q/K/V chained) ----------
// 16 rows/block, grid 256. Same fragment algebra as verified k_edge/k_ffn:
// A = W^T frag A[m=outcol c][k=4g+j], B = act frag B[k][n=row c],
// D[m=16ot+4g+r][n=row c]. All outputs staged in LDS -> coalesced writeout.
__global__ __launch_bounds__(256) void k_proj(
    const float* __restrict__ x,
    const float* __restrict__ g1, const float* __restrict__ b1,
    const float* __restrict__ Wp, const float* __restrict__ bp,
    const float* __restrict__ Wq, const float* __restrict__ Wk, const float* __restrict__ Wv,
    float* __restrict__ xp, _Float16* __restrict__ Qh, _Float16* __restrict__ Kh, _Float16* __restrict__ Vh)
{
  __shared__ _Float16 xln[16][136];     // 4.35KB (pad 136: 272B rows, 16B-aligned)
  __shared__ _Float16 xps[16][136];     // 4.35KB
  __shared__ float    xp32[16][132];    // 8.45KB (pad 132)
  __shared__ _Float16 qs[3][16][136];   // 13.1KB
  int tid=threadIdx.x, w=tid>>6, lane=tid&63;
  int c=lane&15, g=lane>>4;
  int row0 = blockIdx.x*16;
  int b = row0>>9, n0 = row0&(NN-1);

  // ---- LN1: wave w handles rows {w, w+4, w+8, w+12}
  float ga=g1[lane], gb=g1[lane+64], ba=b1[lane], bbx=b1[lane+64];
#pragma unroll
  for (int rr=0;rr<4;++rr){
    int r = w + rr*4;
    size_t gi = (size_t)(row0+r)*DINC + lane;
    float a = x[gi], cc = x[gi+64];
    float s = wsum(a+cc);
    float q = wsum(a*a+cc*cc);
    float mean = s*(1.f/DINC);
    float var  = q*(1.f/DINC)-mean*mean;
    float rstd = rsqrtf(var+1e-5f);
    xln[r][lane]    = (_Float16)((a -mean)*rstd*ga + ba);
    xln[r][lane+64] = (_Float16)((cc-mean)*rstd*gb + bbx);
  }
  __syncthreads();

  // ---- phase 1: xp = xln @ Wp + bp ; wave w -> out tiles {2w, 2w+1}
#pragma unroll
  for (int oo=0;oo<2;++oo){
    int ot = 2*w+oo;
    float4 bi = *(const float4*)(bp + 16*ot + 4*g);
    f32x4 D; D[0]=bi.x; D[1]=bi.y; D[2]=bi.z; D[3]=bi.w;
#pragma unroll
    for (int kt=0;kt<8;++kt){
      h4 f;
#pragma unroll
      for (int j=0;j<4;++j)
        f[j] = (_Float16)Wp[(size_t)(16*kt+4*g+j)*DOUTC + 16*ot + c];
      h4 hb = *(const h4*)&xln[c][16*kt+4*g];
      D = __builtin_amdgcn_mfma_f32_16x16x16f16(f, hb, D, 0,0,0);
    }
#pragma unroll
    for (int r=0;r<4;++r){
      xp32[c][16*ot+4*g+r] = D[r];
      xps [c][16*ot+4*g+r] = (_Float16)D[r];
    }
  }
  __syncthreads();

  // ---- phase 2: Q/K/V = xps @ W{q,k,v}; 24 (mat,ot) pairs striped over waves
#pragma unroll
  for (int pp=0;pp<6;++pp){
    int p = w + pp*4;                   // 0..23
    int mat = p>>3, ot = p&7;
    const float* W = (mat==0)? Wq : ((mat==1)? Wk : Wv);
    f32x4 D = {0.f,0.f,0.f,0.f};
#pragma unroll
    for (int kt=0;kt<8;++kt){
      h4 f;
#pragma unroll
      for (int j=0;j<4;++j)
        f[j] = (_Float16)W[(size_t)(16*kt+4*g+j)*DOUTC + 16*ot + c];
      h4 hb = *(const h4*)&xps[c][16*kt+4*g];
      D = __builtin_amdgcn_mfma_f32_16x16x16f16(f, hb, D, 0,0,0);
    }
#pragma unroll
    for (int r=0;r<4;++r)
      qs[mat][c][16*ot+4*g+r] = (_Float16)D[r];
  }
  __syncthreads();

  // ---- coalesced writeout: xp (f32) + Q/K/V (f16, [b,h,n,d])
#pragma unroll
  for (int i=tid;i<512;i+=256){
    int r=i>>5, seg=i&31;
    *(float4*)(xp + (size_t)(row0+r)*DOUTC + seg*4) = *(const float4*)&xp32[r][seg*4];
  }
#pragma unroll
  for (int mat=0;mat<3;++mat){
    int r = tid>>4, seg = tid&15;
    int h = seg>>1, d = (seg&1)*8;
    _Float16* O = (mat==0)? Qh : ((mat==1)? Kh : Vh);
    *(float4*)(O + (((size_t)b*HHC+h)*NN + n0+r)*DHC + d) = *(const float4*)&qs[mat][r][seg*8];
  }
}

// ---------- edge-bias MLP v4 (R10-verified, unchanged): per-row compaction ----------
__global__ __launch_bounds__(256) void k_edge(
  const float* __restrict__ ea, const int* __restrict__ adj,
  const float* __restrict__ eg, const float* __restrict__ ebi,
  const float* __restrict__ We1, const float* __restrict__ be1,
  const float* __restrict__ We2, const float* __restrict__ be2,
  _Float16* __restrict__ ebias)
{
  __shared__ _Float16 stage[8][520];
  __shared__ unsigned long long msk[8];
  __shared__ unsigned short idx16[512];
  __shared__ int cntS;

  int tid = threadIdx.x, w = tid>>6, lane = tid&63;
  int c = lane&15, g = lane>>4;
  int bn = blockIdx.x;
  int b = bn >> 9, n = bn & (NN-1);

  const int* adjRow = adj + (size_t)bn*NN;
  int col1 = tid, col2 = tid + 256;
  int v1 = (adjRow[col1] != 0) || (col1 == n);
  int v2 = (adjRow[col2] != 0) || (col2 == n);
  unsigned long long b1m = __ballot(v1);
  unsigned long long b2m = __ballot(v2);
  if (lane==0){ msk[w] = b1m; msk[4+w] = b2m; }

  h4 w1a,w1b,w2a,w2b;
#pragma unroll
  for (int j=0;j<4;++j){
    w1a[j] = (_Float16)We1[(4*g+j)*32 + c];
    w1b[j] = (_Float16)We1[(4*g+j)*32 + 16 + c];
    w2a[j] = (_Float16)((c<8)? We2[(4*g+j)*HHC + c] : 0.f);
    w2b[j] = (_Float16)((c<8)? We2[(16+4*g+j)*HHC + c] : 0.f);
  }
  float4 b1a = *(const float4*)(be1 + 4*g);
  float4 b1b = *(const float4*)(be1 + 16 + 4*g);
  float4 b2r = *(const float4*)(be2 + (g&1)*4);
  float4 G4  = *(const float4*)(eg  + 4*g);
  float4 Bv4 = *(const float4*)(ebi + 4*g);

  __syncthreads();

  int offs[8]; int cnt = 0;
#pragma unroll
  for (int k=0;k<8;++k){ offs[k] = cnt; cnt += __popcll(msk[k]); }
  if (tid==0) cntS = cnt;

  {
    _Float16 neg = (_Float16)(-30000.f);
    h4 negv; negv[0]=neg; negv[1]=neg; negv[2]=neg; negv[3]=neg;
#pragma unroll
    for (int i=tid;i<1024;i+=256){
      int h = i>>7, m4 = i&127;
      *(h4*)&stage[h][m4*4] = negv;
    }
  }

  if (v1){
    int pos = offs[w]   + __popcll(msk[w]   & ((1ull<<lane)-1ull));
    idx16[pos] = (unsigned short)col1;
  }
  if (v2){
    int pos = offs[4+w] + __popcll(msk[4+w] & ((1ull<<lane)-1ull));
    idx16[pos] = (unsigned short)col2;
  }
  __syncthreads();

  cnt = cntS;
  int nt = (cnt + 15) >> 4;
  const float* eaRow = ea + (size_t)bn*NN*EEC;

  for (int t = w; t < nt; t += 4){
    int slot = 16*t + c;
    int sidx = slot < cnt ? slot : cnt-1;
    int idx  = idx16[sidx];
    float4 v = *(const float4*)(eaRow + (size_t)idx*EEC + 4*g);
    float s = v.x+v.y+v.z+v.w;
    float q = v.x*v.x+v.y*v.y+v.z*v.z+v.w*v.w;
    s += __shfl_xor(s,16); s += __shfl_xor(s,32);
    q += __shfl_xor(q,16); q += __shfl_xor(q,32);
    float mean = s*(1.f/EEC);
    float var  = q*(1.f/EEC) - mean*mean;
    float rstd = rsqrtf(var + 1e-5f);
    h4 ef;
    ef[0]=(_Float16)((v.x-mean)*rstd*G4.x + Bv4.x);
    ef[1]=(_Float16)((v.y-mean)*rstd*G4.y + Bv4.y);
    ef[2]=(_Float16)((v.z-mean)*rstd*G4.z + Bv4.z);
    ef[3]=(_Float16)((v.w-mean)*rstd*G4.w + Bv4.w);
    f32x4 d1a = {b1a.x,b1a.y,b1a.z,b1a.w};
    f32x4 d1b = {b1b.x,b1b.y,b1b.z,b1b.w};
    d1a = __builtin_amdgcn_mfma_f32_16x16x16f16(w1a, ef, d1a, 0,0,0);
    d1b = __builtin_amdgcn_mfma_f32_16x16x16f16(w1b, ef, d1b, 0,0,0);
    h4 hfa,hfb;
#pragma unroll
    for (int r=0;r<4;++r){
      hfa[r]=(_Float16)fmaxf(d1a[r],0.f);
      hfb[r]=(_Float16)fmaxf(d1b[r],0.f);
    }
    f32x4 d2 = {0.f,0.f,0.f,0.f};
    d2 = __builtin_amdgcn_mfma_f32_16x16x16f16(w2a, hfa, d2, 0,0,0);
    d2 = __builtin_amdgcn_mfma_f32_16x16x16f16(w2b, hfb, d2, 0,0,0);
    if (g<2 && slot<cnt){
#pragma unroll
      for (int r=0;r<4;++r){
        float y = d2[r] + ((const float*)&b2r)[r];
        y = fminf(fmaxf(2.f*y,-30.f),30.f);
        float ex = __expf(y);
        float t2 = (ex-1.f)/(ex+1.f);
        stage[4*g+r][idx] = (_Float16)(5.f*t2);
      }
    }
  }
  __syncthreads();

  size_t base = ((size_t)b*HHC)*NN*NN + (size_t)n*NN;
#pragma unroll
  for (int i=tid;i<512;i+=256){
    int h = i>>6, m8 = i&63;
    *(float4*)(ebias + base + (size_t)h*NN*NN + m8*8) =
        *(const float4*)&stage[h][m8*8];
  }
}

// ---------- MFMA attention (R9/R10-verified, unchanged) ----------
__global__ __launch_bounds__(256) void k_attn(
  const _Float16* __restrict__ Qh, const _Float16* __restrict__ Kh, const _Float16* __restrict__ Vh,
  const _Float16* __restrict__ eb, float* __restrict__ ctxb)
{
  __shared__ _Float16 Klds[NN*DHC];
  __shared__ _Float16 Vt[DHC*520];
  int tid = threadIdx.x;
  int bh   = blockIdx.x >> 3;
  int tile = blockIdx.x & 7;
  const _Float16* Kg = Kh + (size_t)bh*NN*DHC;
  const _Float16* Vg = Vh + (size_t)bh*NN*DHC;
  {
    const float4* src = (const float4*)Kg;
    float4* dst = (float4*)Klds;
#pragma unroll
    for (int i=tid;i<1024;i+=256) dst[i]=src[i];
  }
  {
#pragma unroll
    for (int i=tid;i<1024;i+=256){
      int m = i>>1, hf = i&1;
      float4 v4 = *(const float4*)(Vg + (size_t)m*DHC + hf*8);
      const _Float16* hh = (const _Float16*)&v4;
#pragma unroll
      for (int jj=0;jj<8;++jj) Vt[(hf*8+jj)*520 + m] = hh[jj];
    }
  }
  __syncthreads();

  int w = tid>>6, lane = tid&63;
  int c = lane&15, g = lane>>4;
  int n0 = tile*64 + w*16;

  h4 qf = *(const h4*)(Qh + ((size_t)bh*NN + n0 + c)*DHC + 4*g);
  const _Float16* ebw = eb + ((size_t)bh*NN + n0 + c)*NN + 4*g;

  f32x4 zero = {0.f,0.f,0.f,0.f};
  f32x4 acc = zero;
  float rowsum = 0.f;
#pragma unroll
  for (int t=0;t<32;++t){
    h4 kf = *(const h4*)(Klds + (16*t + c)*DHC + 4*g);
    f32x4 d = __builtin_amdgcn_mfma_f32_16x16x16f16(kf, qf, zero, 0, 0, 0);
    h4 e4 = *(const h4*)(ebw + 16*t);
    h4 pa;
#pragma unroll
    for (int r=0;r<4;++r){
      float sv = d[r]*0.25f + (float)e4[r];
      sv = fmaxf(sv,0.f) + 0.2f*fminf(sv,0.f);
      float p = __expf(sv - 6.f);
      rowsum += p;
      pa[r] = (_Float16)p;
    }
    h4 vf = *(const h4*)(Vt + c*520 + 16*t + 4*g);
    acc = __builtin_amdgcn_mfma_f32_16x16x16f16(pa, vf, acc, 0, 0, 0);
  }
  rowsum += __shfl_xor(rowsum,16);
  rowsum += __shfl_xor(rowsum,32);

  int b = bh>>3, h = bh&7;
#pragma unroll
  for (int r=0;r<4;++r){
    float sr = __shfl(rowsum, g*16 + 4*g + r);
    ctxb[((size_t)b*NN + n0 + 4*g + r)*DOUTC + h*DHC + c] = acc[r]/sr;
  }
}

// ---------- FFN v4: 8 rows/block (grid 512 -> 2 blocks/CU; was 1 wave/SIMD) ----------
__global__ __launch_bounds__(256) void k_ffn(
  const float* __restrict__ xp, const float* __restrict__ ctxb,
  const float* __restrict__ g2, const float* __restrict__ b2v,
  const float* __restrict__ W1, const float* __restrict__ bb1,
  const float* __restrict__ W2, const float* __restrict__ bb2,
  float* __restrict__ out)
{
  __shared__ float    hrow[8][DOUTC];        // 4KB residual (8 rows)
  __shared__ _Float16 hn[16][136];           // 4.25KB (rows 8..15 zeroed)
  __shared__ float    part[4][8][16][16];    // 32KB layer-2 partials

  int tid = threadIdx.x, w = tid>>6, lane = tid&63;
  int c = lane&15, g = lane>>4;
  int n0 = blockIdx.x * 8;

  // zero hn rows 8..15 (flat h4: rows 8-15 = h4 indices 272..543)
#pragma unroll
  for (int i=tid;i<272;i+=256){
    h4 z = {(_Float16)0.f,(_Float16)0.f,(_Float16)0.f,(_Float16)0.f};
    ((h4*)hn)[272+i] = z;
  }

  float ga=g2[lane], gb=g2[lane+64], ba=b2v[lane], bbx=b2v[lane+64];
#pragma unroll
  for (int rr=0;rr<2;++rr){
    int r = w + rr*4;
    size_t gi = (size_t)(n0+r)*DOUTC + lane;
    float a  = xp[gi]    + ctxb[gi];
    float cc = xp[gi+64] + ctxb[gi+64];
    hrow[r][lane] = a; hrow[r][lane+64] = cc;
    float s = wsum(a+cc);
    float q = wsum(a*a+cc*cc);
    float mean = s*(1.f/DOUTC);
    float var  = q*(1.f/DOUTC) - mean*mean;
    float rstd = rsqrtf(var + 1e-5f);
    hn[r][lane]    = (_Float16)((a -mean)*rstd*ga + ba);
    hn[r][lane+64] = (_Float16)((cc-mean)*rstd*gb + bbx);
  }
  __syncthreads();

  // layer 1, streamed w1 fragments; wave w owns hid tiles 4w..4w+3
  h4 hidB[4];
#pragma unroll
  for (int t=0;t<4;++t){
    int ht = 4*w + t;
    float4 bi = *(const float4*)(bb1 + 16*ht + 4*g);
    f32x4 D1; D1[0]=bi.x; D1[1]=bi.y; D1[2]=bi.z; D1[3]=bi.w;
#pragma unroll
    for (int kt=0;kt<8;++kt){
      h4 f;
#pragma unroll
      for (int j=0;j<4;++j)
        f[j] = (_Float16)W1[(size_t)(16*kt + 4*g + j)*256 + 16*ht + c];
      h4 hb = *(const h4*)&hn[c][16*kt + 4*g];
      D1 = __builtin_amdgcn_mfma_f32_16x16x16f16(f, hb, D1, 0,0,0);
    }
#pragma unroll
    for (int r=0;r<4;++r) hidB[t][r] = (_Float16)fmaxf(D1[r], 0.f);
  }

  // layer 2, ot-major write-through
#pragma unroll
  for (int ot=0;ot<8;++ot){
    f32x4 d2 = {0.f,0.f,0.f,0.f};
#pragma unroll
    for (int t=0;t<4;++t){
      h4 f;
#pragma unroll
      for (int j=0;j<4;++j)
        f[j] = (_Float16)W2[(size_t)(16*(4*w+t) + 4*g + j)*128 + 16*ot + c];
      d2 = __builtin_amdgcn_mfma_f32_16x16x16f16(f, hidB[t], d2, 0,0,0);
    }
#pragma unroll
    for (int r=0;r<4;++r) part[w][ot][4*g+r][c] = d2[r];
  }
  __syncthreads();

#pragma unroll
  for (int i=tid;i<1024;i+=256){
    int n = i>>7, col = i&127;
    int ot = col>>4, m = col&15;
    float v = part[0][ot][m][n] + part[1][ot][m][n]
            + part[2][ot][m][n] + part[3][ot][m][n];
    out[(size_t)(n0+n)*DOUTC + col] = hrow[n][col] + v + bb2[col];
  }
}

extern "C" void kernel_launch(void* const* d_in, const int* in_sizes, int n_in,
                              void* d_out, int out_size, void* d_ws, size_t ws_size,
                              hipStream_t stream)
{
  const float* x     = (const float*)d_in[0];
  const int*   adj   = (const int*)  d_in[1];
  const float* ea    = (const float*)d_in[2];
  const float* ln1_g = (const float*)d_in[3];
  const float* ln1_b = (const float*)d_in[4];
  const float* Wp    = (const float*)d_in[5];
  const float* bp    = (const float*)d_in[6];
  const float* eln_g = (const float*)d_in[7];
  const float* eln_b = (const float*)d_in[8];
  const float* We1   = (const float*)d_in[9];
  const float* be1   = (const float*)d_in[10];
  const float* We2   = (const float*)d_in[11];
  const float* be2   = (const float*)d_in[12];
  const float* Wq    = (const float*)d_in[13];
  const float* Wk    = (const float*)d_in[14];
  const float* Wv    = (const float*)d_in[15];
  const float* ffW1  = (const float*)d_in[16];
  const float* ffb1  = (const float*)d_in[17];
  const float* ffW2  = (const float*)d_in[18];
  const float* ffb2  = (const float*)d_in[19];
  const float* ln2_g = (const float*)d_in[20];
  const float* ln2_b = (const float*)d_in[21];
  float* out = (float*)d_out;

  char* ws = (char*)d_ws;
  float*    xp  = (float*)(ws);                       // 2MB
  float*    ctx = (float*)(ws + ((size_t)2<<20));     // 2MB
  _Float16* Qh  = (_Float16*)(ws + ((size_t)4<<20));  // 1MB
  _Float16* Kh  = (_Float16*)(ws + ((size_t)5<<20));  // 1MB
  _Float16* Vh  = (_Float16*)(ws + ((size_t)6<<20));  // 1MB
  _Float16* ebf = (_Float16*)(ws + ((size_t)7<<20));  // 32MB [B,H,N,N] f16 (mask baked)

  k_proj<<<(BB*NN)/16, 256, 0, stream>>>(x, ln1_g, ln1_b, Wp, bp, Wq, Wk, Wv, xp, Qh, Kh, Vh);
  k_edge<<<BB*NN, 256, 0, stream>>>(ea, adj, eln_g, eln_b, We1, be1, We2, be2, ebf);
  k_attn<<<BB*HHC*8, 256, 0, stream>>>(Qh, Kh, Vh, ebf, ctx);
  k_ffn<<<(BB*NN)/8, 256, 0, stream>>>(xp, ctx, ln2_g, ln2_b, ffW1, ffb1, ffW2, ffb2, out);
}